// Round 1
// baseline (1689.936 us; speedup 1.0000x reference)
//
#include <hip/hip_runtime.h>
#include <hip/hip_bf16.h>
#include <math.h>

#define L_  4096
#define D_  256
#define DI_ 512
#define NS_ 16
#define NC_ 64
#define CH_ 64

// ---------------- embed ----------------
__global__ __launch_bounds__(256) void embed_kernel(const int* __restrict__ ids,
    const float* __restrict__ ew, float* __restrict__ res) {
  int idx = blockIdx.x * 256 + threadIdx.x;
  int l = idx >> 8, d = idx & 255;
  res[idx] = ew[ids[l] * D_ + d];
}

// ---------------- rmsnorm (optionally residual += hadd first) ----------------
__global__ __launch_bounds__(256) void rmsnorm_kernel(float* __restrict__ residual,
    const float* __restrict__ hadd, const float* __restrict__ w, float* __restrict__ out) {
  int l = blockIdx.x;
  int d = threadIdx.x;
  size_t o = (size_t)l * D_ + d;
  float v = residual[o];
  if (hadd) { v += hadd[o]; residual[o] = v; }
  float sq = v * v;
  #pragma unroll
  for (int s = 32; s > 0; s >>= 1) sq += __shfl_down(sq, s, 64);
  __shared__ float ws_[4];
  int wave = d >> 6, lane = d & 63;
  if (lane == 0) ws_[wave] = sq;
  __syncthreads();
  float total = ws_[0] + ws_[1] + ws_[2] + ws_[3];
  float scale = rsqrtf(total * (1.f / D_) + 1e-5f);
  out[o] = v * scale * w[d];
}

// ---------------- C[m,n] = sum_k (A[m,k] (+A2[m,k])) * W[n,k] ----------------
__global__ __launch_bounds__(256) void gemm_nt(const float* __restrict__ A,
    const float* __restrict__ A2, const float* __restrict__ W, float* __restrict__ C,
    int M, int N, int K) {
  __shared__ float As[16][65];
  __shared__ float Ws[16][65];
  int bn = blockIdx.x * 64, bm = blockIdx.y * 64;
  int tid = threadIdx.x;
  int tx = tid & 15, ty = tid >> 4;
  float acc[4][4] = {};
  for (int k0 = 0; k0 < K; k0 += 16) {
    #pragma unroll
    for (int i = 0; i < 4; ++i) {
      int e = tid + i * 256;
      int kk = e & 15, mm = e >> 4;
      float av = A[(size_t)(bm + mm) * K + k0 + kk];
      if (A2) av += A2[(size_t)(bm + mm) * K + k0 + kk];
      As[kk][mm] = av;
      Ws[kk][mm] = W[(size_t)(bn + mm) * K + k0 + kk];
    }
    __syncthreads();
    #pragma unroll
    for (int kk = 0; kk < 16; ++kk) {
      float a[4], b[4];
      #pragma unroll
      for (int i = 0; i < 4; ++i) a[i] = As[kk][ty * 4 + i];
      #pragma unroll
      for (int j = 0; j < 4; ++j) b[j] = Ws[kk][tx * 4 + j];
      #pragma unroll
      for (int i = 0; i < 4; ++i)
        #pragma unroll
        for (int j = 0; j < 4; ++j) acc[i][j] = fmaf(a[i], b[j], acc[i][j]);
    }
    __syncthreads();
  }
  #pragma unroll
  for (int i = 0; i < 4; ++i)
    #pragma unroll
    for (int j = 0; j < 4; ++j)
      C[(size_t)(bm + ty * 4 + i) * N + bn + tx * 4 + j] = acc[i][j];
}

// ---------------- causal depthwise conv (dir-aware) + SiLU ----------------
// uc[dir][l, d] = silu(cb[d] + sum_k cw[d,k] * u_frame[l-3+k, d]) where
// u_frame[t] = xz[pos(t)*1024 + d], pos = dir ? L-1-t : t
__global__ __launch_bounds__(256) void conv_silu_kernel(const float* __restrict__ xz,
    const float* __restrict__ cw, const float* __restrict__ cb, float* __restrict__ uc) {
  int dir = blockIdx.y;
  int idx = blockIdx.x * 256 + threadIdx.x;
  int d = idx & (DI_ - 1), l = idx >> 9;
  const float* w = cw + (size_t)dir * DI_ * 4 + (size_t)d * 4;
  float acc = cb[(size_t)dir * DI_ + d];
  #pragma unroll
  for (int k = 0; k < 4; ++k) {
    int lf = l - 3 + k;
    if (lf >= 0) {
      int pos = dir ? (L_ - 1 - lf) : lf;
      acc = fmaf(w[k], xz[(size_t)pos * 1024 + d], acc);
    }
  }
  float s = acc / (1.f + expf(-acc));
  uc[(size_t)dir * L_ * DI_ + (size_t)l * DI_ + d] = s;
}

// ---------------- xdb[dir][l, 0:48] = uc[dir][l,:] @ W[dir]^T ----------------
__global__ __launch_bounds__(256) void xproj_kernel(const float* __restrict__ uc,
    const float* __restrict__ W, float* __restrict__ xdb) {
  __shared__ float ulds[4][DI_];
  int dir = blockIdx.y;
  int l0 = blockIdx.x * 4;
  int wave = threadIdx.x >> 6, lane = threadIdx.x & 63;
  const float* ucd = uc + (size_t)dir * L_ * DI_;
  #pragma unroll
  for (int i = 0; i < 8; ++i) {
    int e = threadIdx.x + i * 256;
    int r = e >> 9, k = e & (DI_ - 1);
    ulds[r][k] = ucd[(size_t)(l0 + r) * DI_ + k];
  }
  __syncthreads();
  if (lane < 48) {
    const float4* Wr = (const float4*)(W + (size_t)dir * 48 * DI_ + (size_t)lane * DI_);
    const float4* Ur = (const float4*)(ulds[wave]);
    float acc = 0.f;
    #pragma unroll 4
    for (int k = 0; k < DI_ / 4; ++k) {
      float4 w4 = Wr[k], u4 = Ur[k];
      acc = fmaf(w4.x, u4.x, fmaf(w4.y, u4.y, fmaf(w4.z, u4.z, fmaf(w4.w, u4.w, acc))));
    }
    xdb[((size_t)dir * L_ + l0 + wave) * 48 + lane] = acc;
  }
}

// ---------------- dt[dir][l,d] = softplus(xdb[dir][l,0:16] @ dtw[d,:] + dtb[d]) ----------------
__global__ __launch_bounds__(256) void dtproj_kernel(const float* __restrict__ xdb,
    const float* __restrict__ dtw, const float* __restrict__ dtbp, float* __restrict__ dt) {
  int dir = blockIdx.y;
  int idx = blockIdx.x * 256 + threadIdx.x;
  int d = idx & (DI_ - 1), l = idx >> 9;
  const float4* wr = (const float4*)(dtw + (size_t)dir * DI_ * 16 + (size_t)d * 16);
  const float4* xr = (const float4*)(xdb + ((size_t)dir * L_ + l) * 48);
  float acc = dtbp[(size_t)dir * DI_ + d];
  #pragma unroll
  for (int q = 0; q < 4; ++q) {
    float4 w4 = wr[q];
    float4 x4 = xr[q];
    acc = fmaf(w4.x, x4.x, fmaf(w4.y, x4.y, fmaf(w4.z, x4.z, fmaf(w4.w, x4.w, acc))));
  }
  float sp = acc > 20.f ? acc : log1pf(expf(acc));
  dt[(size_t)dir * L_ * DI_ + (size_t)l * DI_ + d] = sp;
}

// ---------------- scan pass1: per-chunk P = prod dA, Q = local scan ----------------
__global__ __launch_bounds__(256) void scan_pass1(const float* __restrict__ dt,
    const float* __restrict__ uc, const float* __restrict__ xdb,
    const float* __restrict__ A_log, float* __restrict__ Pb, float* __restrict__ Qb) {
  int dir = blockIdx.y;
  int c = blockIdx.x >> 5;
  int sub = blockIdx.x & 31;
  int t0 = sub * 256 + threadIdx.x;       // 0..8191 = d*16+n
  int d = t0 >> 4, n = t0 & 15;
  const float Av = -expf(A_log[(size_t)dir * DI_ * NS_ + (size_t)d * NS_ + n]);
  const float* dtd = dt + (size_t)dir * L_ * DI_;
  const float* ud  = uc + (size_t)dir * L_ * DI_;
  const float* xd  = xdb + (size_t)dir * L_ * 48;
  float P = 1.f, Q = 0.f;
  int lbase = c * CH_;
  for (int t = 0; t < CH_; ++t) {
    int l = lbase + t;
    float dtv = dtd[(size_t)l * DI_ + d];
    float uv  = ud[(size_t)l * DI_ + d];
    float bv  = xd[(size_t)l * 48 + 16 + n];
    float dA  = expf(dtv * Av);
    P *= dA;
    Q = fmaf(dA, Q, dtv * bv * uv);
  }
  size_t o = ((size_t)dir * NC_ + c) * 8192 + t0;
  Pb[o] = P; Qb[o] = Q;
}

// ---------------- combine: sequential over chunks, record chunk-entry states ----------------
__global__ __launch_bounds__(256) void scan_combine(const float* __restrict__ Pb,
    const float* __restrict__ Qb, float* __restrict__ H0) {
  int idx = blockIdx.x * 256 + threadIdx.x; // 0..16383
  int dir = idx >> 13; int s = idx & 8191;
  float h = 0.f;
  for (int c = 0; c < NC_; ++c) {
    size_t o = ((size_t)dir * NC_ + c) * 8192 + s;
    H0[o] = h;
    h = fmaf(Pb[o], h, Qb[o]);
  }
}

// ---------------- scan pass2: replay with h0, emit gated y at original pos ----------------
__global__ __launch_bounds__(256) void scan_pass2(const float* __restrict__ dt,
    const float* __restrict__ uc, const float* __restrict__ xdb,
    const float* __restrict__ A_log, const float* __restrict__ Dp,
    const float* __restrict__ xz, const float* __restrict__ H0, float* __restrict__ yg) {
  int dir = blockIdx.y;
  int c = blockIdx.x >> 5;
  int sub = blockIdx.x & 31;
  int t0 = sub * 256 + threadIdx.x;
  int d = t0 >> 4, n = t0 & 15;
  const float Av = -expf(A_log[(size_t)dir * DI_ * NS_ + (size_t)d * NS_ + n]);
  const float Dv = Dp[(size_t)dir * DI_ + d];
  const float* dtd = dt + (size_t)dir * L_ * DI_;
  const float* ud  = uc + (size_t)dir * L_ * DI_;
  const float* xd  = xdb + (size_t)dir * L_ * 48;
  float* ygd = yg + (size_t)dir * L_ * DI_;
  float h = H0[((size_t)dir * NC_ + c) * 8192 + t0];
  for (int t = 0; t < CH_; ++t) {
    int l = c * CH_ + t;
    float dtv = dtd[(size_t)l * DI_ + d];
    float uv  = ud[(size_t)l * DI_ + d];
    float bv  = xd[(size_t)l * 48 + 16 + n];
    float cv  = xd[(size_t)l * 48 + 32 + n];
    float dA  = expf(dtv * Av);
    h = fmaf(dA, h, dtv * bv * uv);
    float yv = h * cv;
    yv += __shfl_xor(yv, 1, 64);
    yv += __shfl_xor(yv, 2, 64);
    yv += __shfl_xor(yv, 4, 64);
    yv += __shfl_xor(yv, 8, 64);
    if (n == 0) {
      int pos = dir ? (L_ - 1 - l) : l;
      float zv = xz[(size_t)pos * 1024 + DI_ + d];
      float g = zv / (1.f + expf(-zv));
      ygd[(size_t)pos * DI_ + d] = (yv + uv * Dv) * g;
    }
  }
}

extern "C" void kernel_launch(void* const* d_in, const int* in_sizes, int n_in,
                              void* d_out, int out_size, void* d_ws, size_t ws_size,
                              hipStream_t stream) {
  const int*   ids       = (const int*)  d_in[0];
  const float* embed_w   = (const float*)d_in[1];
  const float* norm_w    = (const float*)d_in[2];
  const float* in_proj_w = (const float*)d_in[3];
  const float* out_proj_w= (const float*)d_in[4];
  const float* conv_w    = (const float*)d_in[5];
  const float* conv_b    = (const float*)d_in[6];
  const float* x_proj_w  = (const float*)d_in[7];
  const float* dt_proj_w = (const float*)d_in[8];
  const float* dt_proj_b = (const float*)d_in[9];
  const float* A_log     = (const float*)d_in[10];
  const float* Dp        = (const float*)d_in[11];
  const float* norm_f_w  = (const float*)d_in[12];

  float* ws = (float*)d_ws;
  float* residual = ws; ws += (size_t)L_ * D_;
  float* hn       = ws; ws += (size_t)L_ * D_;
  float* xz       = ws; ws += (size_t)L_ * 1024;
  float* uc       = ws; ws += (size_t)2 * L_ * DI_;
  float* xdb      = ws; ws += (size_t)2 * L_ * 48;
  float* dtb_     = ws; ws += (size_t)2 * L_ * DI_;
  float* yg       = ws; ws += (size_t)2 * L_ * DI_;
  float* hbuf     = ws; ws += (size_t)L_ * D_;
  float* Pb       = ws; ws += (size_t)2 * NC_ * 8192;
  float* Qb       = ws; ws += (size_t)2 * NC_ * 8192;
  float* H0       = ws; ws += (size_t)2 * NC_ * 8192;

  embed_kernel<<<L_ * D_ / 256, 256, 0, stream>>>(ids, embed_w, residual);

  for (int i = 0; i < 4; ++i) {
    rmsnorm_kernel<<<L_, 256, 0, stream>>>(residual, i ? hbuf : nullptr,
                                           norm_w + (size_t)i * D_, hn);
    gemm_nt<<<dim3(1024 / 64, L_ / 64), 256, 0, stream>>>(
        hn, nullptr, in_proj_w + (size_t)i * 1024 * D_, xz, L_, 1024, D_);
    dim3 gdi(L_ * DI_ / 256, 2);
    conv_silu_kernel<<<gdi, 256, 0, stream>>>(
        xz, conv_w + (size_t)i * 2 * DI_ * 4, conv_b + (size_t)i * 2 * DI_, uc);
    xproj_kernel<<<dim3(L_ / 4, 2), 256, 0, stream>>>(
        uc, x_proj_w + (size_t)i * 2 * 48 * DI_, xdb);
    dtproj_kernel<<<gdi, 256, 0, stream>>>(
        xdb, dt_proj_w + (size_t)i * 2 * DI_ * 16, dt_proj_b + (size_t)i * 2 * DI_, dtb_);
    dim3 gsc(NC_ * 32, 2);
    scan_pass1<<<gsc, 256, 0, stream>>>(
        dtb_, uc, xdb, A_log + (size_t)i * 2 * DI_ * NS_, Pb, Qb);
    scan_combine<<<64, 256, 0, stream>>>(Pb, Qb, H0);
    scan_pass2<<<gsc, 256, 0, stream>>>(
        dtb_, uc, xdb, A_log + (size_t)i * 2 * DI_ * NS_, Dp + (size_t)i * 2 * DI_,
        xz, H0, yg);
    gemm_nt<<<dim3(D_ / 64, L_ / 64), 256, 0, stream>>>(
        yg, yg + (size_t)L_ * DI_, out_proj_w + (size_t)i * D_ * DI_, hbuf, L_, D_, DI_);
  }

  rmsnorm_kernel<<<L_, 256, 0, stream>>>(residual, hbuf, norm_f_w, (float*)d_out);
}

// Round 2
// 1012.214 us; speedup vs baseline: 1.6695x; 1.6695x over previous
//
#include <hip/hip_runtime.h>
#include <hip/hip_bf16.h>
#include <math.h>

#define L_  4096
#define D_  256
#define DI_ 512
#define NS_ 16
#define NC_ 64
#define CH_ 64

typedef __attribute__((ext_vector_type(8))) short short8;
typedef __attribute__((ext_vector_type(4))) float f32x4;

// ---------------- embed ----------------
__global__ __launch_bounds__(256) void embed_kernel(const int* __restrict__ ids,
    const float* __restrict__ ew, float* __restrict__ res) {
  int idx = blockIdx.x * 256 + threadIdx.x;
  int l = idx >> 8, d = idx & 255;
  res[idx] = ew[ids[l] * D_ + d];
}

// ---------------- weight convert: in_proj -> bf16; out_proj -> duplicated-K bf16 ----------------
__global__ __launch_bounds__(256) void convert_weights(const float* __restrict__ inw,
    const float* __restrict__ outw, __hip_bfloat16* __restrict__ inw_b,
    __hip_bfloat16* __restrict__ outw_b) {
  int idx = blockIdx.x * 256 + threadIdx.x;   // 0 .. 4*1024*256-1  (== 4*256*1024)
  inw_b[idx] = __float2bfloat16(inw[idx]);
  int layer = idx >> 18;          // /(256*1024)
  int rem = idx & 262143;
  int o = rem >> 10, k = rem & 1023;
  outw_b[idx] = __float2bfloat16(outw[((size_t)layer * 256 + o) * 512 + (k & 511)]);
}

// ---------------- rmsnorm (optionally residual += hadd first) ----------------
template<bool BF16OUT>
__global__ __launch_bounds__(256) void rmsnorm_kernel(float* __restrict__ residual,
    const float* __restrict__ hadd, const float* __restrict__ w, void* __restrict__ out) {
  int l = blockIdx.x;
  int d = threadIdx.x;
  size_t o = (size_t)l * D_ + d;
  float v = residual[o];
  if (hadd) { v += hadd[o]; residual[o] = v; }
  float sq = v * v;
  #pragma unroll
  for (int s = 32; s > 0; s >>= 1) sq += __shfl_down(sq, s, 64);
  __shared__ float ws_[4];
  int wave = d >> 6, lane = d & 63;
  if (lane == 0) ws_[wave] = sq;
  __syncthreads();
  float total = ws_[0] + ws_[1] + ws_[2] + ws_[3];
  float scale = rsqrtf(total * (1.f / D_) + 1e-5f);
  float r = v * scale * w[d];
  if (BF16OUT) ((__hip_bfloat16*)out)[o] = __float2bfloat16(r);
  else         ((float*)out)[o] = r;
}

// ---------------- bf16 MFMA GEMM: C[m,n] = sum_k A[m,k]*B[n,k] (B^T layout) ----------------
__device__ __forceinline__ void gload_lds16(const void* g, void* l) {
  __builtin_amdgcn_global_load_lds((const __attribute__((address_space(1))) unsigned int*)g,
                                   (__attribute__((address_space(3))) unsigned int*)l,
                                   16, 0, 0);
}

template<int BM, int BN>
__global__ __launch_bounds__(256) void gemm_bt_bf16(const __hip_bfloat16* __restrict__ A,
    const __hip_bfloat16* __restrict__ B, float* __restrict__ C, int M, int N, int K) {
  constexpr int FM = BM / 32, FN = BN / 32;       // frags per wave (wave tile = BM/2 x BN/2)
  constexpr int ABYTES = BM * 64, BBYTES = BN * 64;
  __shared__ __attribute__((aligned(16))) char As[ABYTES];
  __shared__ __attribute__((aligned(16))) char Bs[BBYTES];
  int tid = threadIdx.x, lane = tid & 63, w = tid >> 6;
  int bm = blockIdx.y * BM, bn = blockIdx.x * BN;
  int wr = (w >> 1) * (BM / 2), wc = (w & 1) * (BN / 2);
  f32x4 acc[FM][FN] = {};
  for (int k0 = 0; k0 < K; k0 += 32) {
    __syncthreads();                               // prev compute done before overwrite
    #pragma unroll
    for (int i = 0; i < ABYTES / 4096; ++i) {
      int x = (i * 256 + tid) * 16;
      int xs = x ^ (((x >> 7) & 3) << 4);          // inverse-swizzled SOURCE, linear dest
      int row = xs >> 6, col = (xs & 63) >> 1;
      gload_lds16(A + (size_t)(bm + row) * K + k0 + col, As + i * 4096 + w * 1024);
    }
    #pragma unroll
    for (int i = 0; i < BBYTES / 4096; ++i) {
      int x = (i * 256 + tid) * 16;
      int xs = x ^ (((x >> 7) & 3) << 4);
      int row = xs >> 6, col = (xs & 63) >> 1;
      gload_lds16(B + (size_t)(bn + row) * K + k0 + col, Bs + i * 4096 + w * 1024);
    }
    __syncthreads();                               // drains vmcnt before barrier
    short8 af[FM], bf[FN];
    #pragma unroll
    for (int m = 0; m < FM; ++m) {
      int row = wr + m * 16 + (lane & 15);
      int x = row * 64 + ((lane >> 4) * 16);
      x ^= ((x >> 7) & 3) << 4;                    // swizzled read
      af[m] = *reinterpret_cast<const short8*>(As + x);
    }
    #pragma unroll
    for (int n = 0; n < FN; ++n) {
      int row = wc + n * 16 + (lane & 15);
      int x = row * 64 + ((lane >> 4) * 16);
      x ^= ((x >> 7) & 3) << 4;
      bf[n] = *reinterpret_cast<const short8*>(Bs + x);
    }
    #pragma unroll
    for (int m = 0; m < FM; ++m)
      #pragma unroll
      for (int n = 0; n < FN; ++n)
        acc[m][n] = __builtin_amdgcn_mfma_f32_16x16x32_bf16(af[m], bf[n], acc[m][n], 0, 0, 0);
  }
  #pragma unroll
  for (int m = 0; m < FM; ++m)
    #pragma unroll
    for (int n = 0; n < FN; ++n)
      #pragma unroll
      for (int j = 0; j < 4; ++j)
        C[(size_t)(bm + wr + m * 16 + (lane >> 4) * 4 + j) * N + bn + wc + n * 16 + (lane & 15)]
            = acc[m][n][j];
}

// ---------------- causal depthwise conv (dir-aware) + SiLU ----------------
__global__ __launch_bounds__(256) void conv_silu_kernel(const float* __restrict__ xz,
    const float* __restrict__ cw, const float* __restrict__ cb, float* __restrict__ uc) {
  int dir = blockIdx.y;
  int idx = blockIdx.x * 256 + threadIdx.x;
  int d = idx & (DI_ - 1), l = idx >> 9;
  const float* w = cw + (size_t)dir * DI_ * 4 + (size_t)d * 4;
  float acc = cb[(size_t)dir * DI_ + d];
  #pragma unroll
  for (int k = 0; k < 4; ++k) {
    int lf = l - 3 + k;
    if (lf >= 0) {
      int pos = dir ? (L_ - 1 - lf) : lf;
      acc = fmaf(w[k], xz[(size_t)pos * 1024 + d], acc);
    }
  }
  float s = acc * __builtin_amdgcn_rcpf(1.f + __expf(-acc));
  uc[(size_t)dir * L_ * DI_ + (size_t)l * DI_ + d] = s;
}

// ---------------- xdb[dir][l, 0:48] = uc[dir][l,:] @ W[dir]^T ----------------
__global__ __launch_bounds__(256) void xproj_kernel(const float* __restrict__ uc,
    const float* __restrict__ W, float* __restrict__ xdb) {
  __shared__ float ulds[4][DI_];
  int dir = blockIdx.y;
  int l0 = blockIdx.x * 4;
  int wave = threadIdx.x >> 6, lane = threadIdx.x & 63;
  const float* ucd = uc + (size_t)dir * L_ * DI_;
  #pragma unroll
  for (int i = 0; i < 8; ++i) {
    int e = threadIdx.x + i * 256;
    int r = e >> 9, k = e & (DI_ - 1);
    ulds[r][k] = ucd[(size_t)(l0 + r) * DI_ + k];
  }
  __syncthreads();
  if (lane < 48) {
    const float4* Wr = (const float4*)(W + (size_t)dir * 48 * DI_ + (size_t)lane * DI_);
    const float4* Ur = (const float4*)(ulds[wave]);
    float acc = 0.f;
    #pragma unroll 4
    for (int k = 0; k < DI_ / 4; ++k) {
      float4 w4 = Wr[k], u4 = Ur[k];
      acc = fmaf(w4.x, u4.x, fmaf(w4.y, u4.y, fmaf(w4.z, u4.z, fmaf(w4.w, u4.w, acc))));
    }
    xdb[((size_t)dir * L_ + l0 + wave) * 48 + lane] = acc;
  }
}

// ---------------- dt[dir][l,d] = softplus(xdb[dir][l,0:16] @ dtw[d,:] + dtb[d]) ----------------
__global__ __launch_bounds__(256) void dtproj_kernel(const float* __restrict__ xdb,
    const float* __restrict__ dtw, const float* __restrict__ dtbp, float* __restrict__ dt) {
  int dir = blockIdx.y;
  int idx = blockIdx.x * 256 + threadIdx.x;
  int d = idx & (DI_ - 1), l = idx >> 9;
  const float4* wr = (const float4*)(dtw + (size_t)dir * DI_ * 16 + (size_t)d * 16);
  const float4* xr = (const float4*)(xdb + ((size_t)dir * L_ + l) * 48);
  float acc = dtbp[(size_t)dir * DI_ + d];
  #pragma unroll
  for (int q = 0; q < 4; ++q) {
    float4 w4 = wr[q];
    float4 x4 = xr[q];
    acc = fmaf(w4.x, x4.x, fmaf(w4.y, x4.y, fmaf(w4.z, x4.z, fmaf(w4.w, x4.w, acc))));
  }
  float sp = acc > 20.f ? acc : __logf(1.f + __expf(acc));
  dt[(size_t)dir * L_ * DI_ + (size_t)l * DI_ + d] = sp;
}

// ---------------- scan pass1: per-chunk P = prod dA, Q = local scan ----------------
// thread = (d, nh): 8 states in registers. block covers 128 d x 2 nh for one chunk quarter.
__global__ __launch_bounds__(256) void scan_pass1(const float* __restrict__ dt,
    const float* __restrict__ uc, const float* __restrict__ xdb,
    const float* __restrict__ A_log, float* __restrict__ Pb, float* __restrict__ Qb) {
  int dir = blockIdx.y;
  int c = blockIdx.x >> 2, q = blockIdx.x & 3;
  int tid = threadIdx.x;
  int dl = tid >> 1, nh = tid & 1;
  int d = q * 128 + dl;
  __shared__ float Bl[CH_][16];
  const float* xd = xdb + ((size_t)dir * L_ + (size_t)c * CH_) * 48;
  #pragma unroll
  for (int i = 0; i < 4; ++i) {
    int e = tid + i * 256;
    Bl[e >> 4][e & 15] = xd[(size_t)(e >> 4) * 48 + 16 + (e & 15)];
  }
  float Av[8], P[8], Q[8];
  const float* Ab = A_log + ((size_t)dir * DI_ + d) * 16 + nh * 8;
  #pragma unroll
  for (int j = 0; j < 8; ++j) { Av[j] = -__expf(Ab[j]); P[j] = 1.f; Q[j] = 0.f; }
  __syncthreads();
  const float* dtd = dt + (size_t)dir * L_ * DI_ + (size_t)c * CH_ * DI_ + d;
  const float* ud  = uc + (size_t)dir * L_ * DI_ + (size_t)c * CH_ * DI_ + d;
  for (int t = 0; t < CH_; ++t) {
    float dtv = dtd[(size_t)t * DI_];
    float uv  = ud[(size_t)t * DI_];
    float du = dtv * uv;
    const float4* Br = (const float4*)&Bl[t][nh * 8];
    float4 b0 = Br[0], b1 = Br[1];
    float bb[8] = {b0.x, b0.y, b0.z, b0.w, b1.x, b1.y, b1.z, b1.w};
    #pragma unroll
    for (int j = 0; j < 8; ++j) {
      float dA = __expf(dtv * Av[j]);
      P[j] *= dA;
      Q[j] = fmaf(dA, Q[j], bb[j] * du);
    }
  }
  size_t ob = ((size_t)dir * NC_ + c) * 8192 + (size_t)(nh * 8) * 512 + d;
  #pragma unroll
  for (int j = 0; j < 8; ++j) { Pb[ob + j * 512] = P[j]; Qb[ob + j * 512] = Q[j]; }
}

// ---------------- combine: sequential over chunks, record chunk-entry states ----------------
__global__ __launch_bounds__(256) void scan_combine(const float* __restrict__ Pb,
    const float* __restrict__ Qb, float* __restrict__ H0) {
  int idx = blockIdx.x * 256 + threadIdx.x; // 0..16383
  int dir = idx >> 13; int s = idx & 8191;
  float h = 0.f;
  for (int c = 0; c < NC_; ++c) {
    size_t o = ((size_t)dir * NC_ + c) * 8192 + s;
    H0[o] = h;
    h = fmaf(Pb[o], h, Qb[o]);
  }
}

// ---------------- scan pass2: replay with h0, emit gated y (bf16, [L][2*512]) ----------------
__global__ __launch_bounds__(256) void scan_pass2(const float* __restrict__ dt,
    const float* __restrict__ uc, const float* __restrict__ xdb,
    const float* __restrict__ A_log, const float* __restrict__ Dp,
    const float* __restrict__ xz, const float* __restrict__ H0,
    __hip_bfloat16* __restrict__ yg) {
  int dir = blockIdx.y;
  int c = blockIdx.x >> 2, q = blockIdx.x & 3;
  int tid = threadIdx.x;
  int dl = tid >> 1, nh = tid & 1;
  int d = q * 128 + dl;
  __shared__ float Bl[CH_][16];
  __shared__ float Cl[CH_][16];
  const float* xd = xdb + ((size_t)dir * L_ + (size_t)c * CH_) * 48;
  #pragma unroll
  for (int i = 0; i < 4; ++i) {
    int e = tid + i * 256;
    Bl[e >> 4][e & 15] = xd[(size_t)(e >> 4) * 48 + 16 + (e & 15)];
    Cl[e >> 4][e & 15] = xd[(size_t)(e >> 4) * 48 + 32 + (e & 15)];
  }
  float Av[8], h[8];
  const float* Ab = A_log + ((size_t)dir * DI_ + d) * 16 + nh * 8;
  size_t ob = ((size_t)dir * NC_ + c) * 8192 + (size_t)(nh * 8) * 512 + d;
  #pragma unroll
  for (int j = 0; j < 8; ++j) { Av[j] = -__expf(Ab[j]); h[j] = H0[ob + j * 512]; }
  float Dv = Dp[(size_t)dir * DI_ + d];
  __syncthreads();
  const float* dtd = dt + (size_t)dir * L_ * DI_ + (size_t)c * CH_ * DI_ + d;
  const float* ud  = uc + (size_t)dir * L_ * DI_ + (size_t)c * CH_ * DI_ + d;
  for (int t = 0; t < CH_; ++t) {
    float dtv = dtd[(size_t)t * DI_];
    float uv  = ud[(size_t)t * DI_];
    float du = dtv * uv;
    const float4* Br = (const float4*)&Bl[t][nh * 8];
    const float4* Cr = (const float4*)&Cl[t][nh * 8];
    float4 b0 = Br[0], b1 = Br[1], c0 = Cr[0], c1 = Cr[1];
    float bb[8] = {b0.x, b0.y, b0.z, b0.w, b1.x, b1.y, b1.z, b1.w};
    float cc[8] = {c0.x, c0.y, c0.z, c0.w, c1.x, c1.y, c1.z, c1.w};
    float y = 0.f;
    #pragma unroll
    for (int j = 0; j < 8; ++j) {
      float dA = __expf(dtv * Av[j]);
      h[j] = fmaf(dA, h[j], bb[j] * du);
      y = fmaf(h[j], cc[j], y);
    }
    y += __shfl_xor(y, 1, 64);
    int l = c * CH_ + t;
    int pos = dir ? (L_ - 1 - l) : l;
    float zv = xz[(size_t)pos * 1024 + DI_ + d];
    float g = zv * __builtin_amdgcn_rcpf(1.f + __expf(-zv));
    if (nh == 0)
      yg[(size_t)pos * 1024 + (size_t)dir * DI_ + d] = __float2bfloat16((y + uv * Dv) * g);
  }
}

extern "C" void kernel_launch(void* const* d_in, const int* in_sizes, int n_in,
                              void* d_out, int out_size, void* d_ws, size_t ws_size,
                              hipStream_t stream) {
  const int*   ids       = (const int*)  d_in[0];
  const float* embed_w   = (const float*)d_in[1];
  const float* norm_w    = (const float*)d_in[2];
  const float* in_proj_w = (const float*)d_in[3];
  const float* out_proj_w= (const float*)d_in[4];
  const float* conv_w    = (const float*)d_in[5];
  const float* conv_b    = (const float*)d_in[6];
  const float* x_proj_w  = (const float*)d_in[7];
  const float* dt_proj_w = (const float*)d_in[8];
  const float* dt_proj_b = (const float*)d_in[9];
  const float* A_log     = (const float*)d_in[10];
  const float* Dp        = (const float*)d_in[11];
  const float* norm_f_w  = (const float*)d_in[12];

  float* ws = (float*)d_ws;
  float* residual = ws; ws += (size_t)L_ * D_;
  float* xz       = ws; ws += (size_t)L_ * 1024;
  float* uc       = ws; ws += (size_t)2 * L_ * DI_;
  float* xdb      = ws; ws += (size_t)2 * L_ * 48;
  float* dtb_     = ws; ws += (size_t)2 * L_ * DI_;
  float* hbuf     = ws; ws += (size_t)L_ * D_;
  float* Pb       = ws; ws += (size_t)2 * NC_ * 8192;
  float* Qb       = ws; ws += (size_t)2 * NC_ * 8192;
  float* H0       = ws; ws += (size_t)2 * NC_ * 8192;
  __hip_bfloat16* hn_b   = (__hip_bfloat16*)ws;
  __hip_bfloat16* yg_b   = hn_b + (size_t)L_ * D_;
  __hip_bfloat16* inw_b  = yg_b + (size_t)L_ * 1024;
  __hip_bfloat16* outw_b = inw_b + (size_t)4 * 1024 * D_;

  embed_kernel<<<L_ * D_ / 256, 256, 0, stream>>>(ids, embed_w, residual);
  convert_weights<<<4 * 1024 * D_ / 256, 256, 0, stream>>>(in_proj_w, out_proj_w, inw_b, outw_b);

  for (int i = 0; i < 4; ++i) {
    rmsnorm_kernel<true><<<L_, 256, 0, stream>>>(residual, i ? hbuf : nullptr,
                                                 norm_w + (size_t)i * D_, hn_b);
    gemm_bt_bf16<64, 64><<<dim3(1024 / 64, L_ / 64), 256, 0, stream>>>(
        hn_b, inw_b + (size_t)i * 1024 * D_, xz, L_, 1024, D_);
    dim3 gdi(L_ * DI_ / 256, 2);
    conv_silu_kernel<<<gdi, 256, 0, stream>>>(
        xz, conv_w + (size_t)i * 2 * DI_ * 4, conv_b + (size_t)i * 2 * DI_, uc);
    xproj_kernel<<<dim3(L_ / 4, 2), 256, 0, stream>>>(
        uc, x_proj_w + (size_t)i * 2 * 48 * DI_, xdb);
    dtproj_kernel<<<gdi, 256, 0, stream>>>(
        xdb, dt_proj_w + (size_t)i * 2 * DI_ * 16, dt_proj_b + (size_t)i * 2 * DI_, dtb_);
    dim3 gsc(NC_ * 4, 2);
    scan_pass1<<<gsc, 256, 0, stream>>>(
        dtb_, uc, xdb, A_log + (size_t)i * 2 * DI_ * NS_, Pb, Qb);
    scan_combine<<<64, 256, 0, stream>>>(Pb, Qb, H0);
    scan_pass2<<<gsc, 256, 0, stream>>>(
        dtb_, uc, xdb, A_log + (size_t)i * 2 * DI_ * NS_, Dp + (size_t)i * 2 * DI_,
        xz, H0, yg_b);
    gemm_bt_bf16<64, 64><<<dim3(D_ / 64, L_ / 64), 256, 0, stream>>>(
        yg_b, outw_b + (size_t)i * D_ * 1024, hbuf, L_, D_, 1024);
  }

  rmsnorm_kernel<false><<<L_, 256, 0, stream>>>(residual, hbuf, norm_f_w, d_out);
}

// Round 3
// 671.400 us; speedup vs baseline: 2.5170x; 1.5076x over previous
//
#include <hip/hip_runtime.h>
#include <hip/hip_bf16.h>
#include <math.h>

#define L_  4096
#define D_  256
#define DI_ 512
#define NS_ 16
#define NC_ 64
#define CH_ 64

typedef __attribute__((ext_vector_type(8))) short short8;
typedef __attribute__((ext_vector_type(4))) float f32x4;

// ---------------- embed ----------------
__global__ __launch_bounds__(256) void embed_kernel(const int* __restrict__ ids,
    const float* __restrict__ ew, float* __restrict__ res) {
  int idx = blockIdx.x * 256 + threadIdx.x;
  int l = idx >> 8, d = idx & 255;
  res[idx] = ew[ids[l] * D_ + d];
}

// ---------------- weight convert: in_proj -> bf16; out_proj -> duplicated-K bf16 ----------------
__global__ __launch_bounds__(256) void convert_weights(const float* __restrict__ inw,
    const float* __restrict__ outw, __hip_bfloat16* __restrict__ inw_b,
    __hip_bfloat16* __restrict__ outw_b) {
  int idx = blockIdx.x * 256 + threadIdx.x;   // 0 .. 4*1024*256-1
  inw_b[idx] = __float2bfloat16(inw[idx]);
  int layer = idx >> 18;
  int rem = idx & 262143;
  int o = rem >> 10, k = rem & 1023;
  outw_b[idx] = __float2bfloat16(outw[((size_t)layer * 256 + o) * 512 + (k & 511)]);
}

// ---------------- x_proj_w -> bf16 padded [4][2][64][512], rows 48..63 = 0 ----------------
__global__ __launch_bounds__(256) void convert_xpw(const float* __restrict__ xpw,
    __hip_bfloat16* __restrict__ xpw_b) {
  int idx = blockIdx.x * 256 + threadIdx.x;   // 0 .. 4*2*64*512-1
  int layer = idx >> 16;
  int rem = idx & 65535;
  int dir = rem >> 15;
  int r = (rem >> 9) & 63, k = idx & 511;
  float v = (r < 48) ? xpw[(((size_t)layer * 2 + dir) * 48 + r) * 512 + k] : 0.f;
  xpw_b[idx] = __float2bfloat16(v);
}

// ---------------- rmsnorm (optionally residual += hadd first) ----------------
template<bool BF16OUT>
__global__ __launch_bounds__(256) void rmsnorm_kernel(float* __restrict__ residual,
    const float* __restrict__ hadd, const float* __restrict__ w, void* __restrict__ out) {
  int l = blockIdx.x;
  int d = threadIdx.x;
  size_t o = (size_t)l * D_ + d;
  float v = residual[o];
  if (hadd) { v += hadd[o]; residual[o] = v; }
  float sq = v * v;
  #pragma unroll
  for (int s = 32; s > 0; s >>= 1) sq += __shfl_down(sq, s, 64);
  __shared__ float ws_[4];
  int wave = d >> 6, lane = d & 63;
  if (lane == 0) ws_[wave] = sq;
  __syncthreads();
  float total = ws_[0] + ws_[1] + ws_[2] + ws_[3];
  float scale = rsqrtf(total * (1.f / D_) + 1e-5f);
  float r = v * scale * w[d];
  if (BF16OUT) ((__hip_bfloat16*)out)[o] = __float2bfloat16(r);
  else         ((float*)out)[o] = r;
}

// ---------------- bf16 MFMA GEMM: C[m,n] = sum_k A[m,k]*B[n,k] (B^T layout), z-batched ----------------
__device__ __forceinline__ void gload_lds16(const void* g, void* l) {
  __builtin_amdgcn_global_load_lds((const __attribute__((address_space(1))) unsigned int*)g,
                                   (__attribute__((address_space(3))) unsigned int*)l,
                                   16, 0, 0);
}

template<int BM, int BN>
__global__ __launch_bounds__(256) void gemm_bt_bf16(const __hip_bfloat16* __restrict__ A,
    const __hip_bfloat16* __restrict__ B, float* __restrict__ C, int M, int N, int K,
    size_t sA, size_t sB, size_t sC) {
  A += (size_t)blockIdx.z * sA; B += (size_t)blockIdx.z * sB; C += (size_t)blockIdx.z * sC;
  constexpr int FM = BM / 32, FN = BN / 32;       // frags per wave (wave tile = BM/2 x BN/2)
  constexpr int ABYTES = BM * 64, BBYTES = BN * 64;
  __shared__ __attribute__((aligned(16))) char As[ABYTES];
  __shared__ __attribute__((aligned(16))) char Bs[BBYTES];
  int tid = threadIdx.x, lane = tid & 63, w = tid >> 6;
  int bm = blockIdx.y * BM, bn = blockIdx.x * BN;
  int wr = (w >> 1) * (BM / 2), wc = (w & 1) * (BN / 2);
  f32x4 acc[FM][FN] = {};
  for (int k0 = 0; k0 < K; k0 += 32) {
    __syncthreads();
    #pragma unroll
    for (int i = 0; i < ABYTES / 4096; ++i) {
      int x = (i * 256 + tid) * 16;
      int xs = x ^ (((x >> 7) & 3) << 4);          // inverse-swizzled SOURCE, linear dest
      int row = xs >> 6, col = (xs & 63) >> 1;
      gload_lds16(A + (size_t)(bm + row) * K + k0 + col, As + i * 4096 + w * 1024);
    }
    #pragma unroll
    for (int i = 0; i < BBYTES / 4096; ++i) {
      int x = (i * 256 + tid) * 16;
      int xs = x ^ (((x >> 7) & 3) << 4);
      int row = xs >> 6, col = (xs & 63) >> 1;
      gload_lds16(B + (size_t)(bn + row) * K + k0 + col, Bs + i * 4096 + w * 1024);
    }
    __syncthreads();
    short8 af[FM], bf[FN];
    #pragma unroll
    for (int m = 0; m < FM; ++m) {
      int row = wr + m * 16 + (lane & 15);
      int x = row * 64 + ((lane >> 4) * 16);
      x ^= ((x >> 7) & 3) << 4;                    // swizzled read
      af[m] = *reinterpret_cast<const short8*>(As + x);
    }
    #pragma unroll
    for (int n = 0; n < FN; ++n) {
      int row = wc + n * 16 + (lane & 15);
      int x = row * 64 + ((lane >> 4) * 16);
      x ^= ((x >> 7) & 3) << 4;
      bf[n] = *reinterpret_cast<const short8*>(Bs + x);
    }
    #pragma unroll
    for (int m = 0; m < FM; ++m)
      #pragma unroll
      for (int n = 0; n < FN; ++n)
        acc[m][n] = __builtin_amdgcn_mfma_f32_16x16x32_bf16(af[m], bf[n], acc[m][n], 0, 0, 0);
  }
  #pragma unroll
  for (int m = 0; m < FM; ++m)
    #pragma unroll
    for (int n = 0; n < FN; ++n)
      #pragma unroll
      for (int j = 0; j < 4; ++j)
        C[(size_t)(bm + wr + m * 16 + (lane >> 4) * 4 + j) * N + bn + wc + n * 16 + (lane & 15)]
            = acc[m][n][j];
}

// ---------------- causal depthwise conv (dir-aware) + SiLU -> bf16 ----------------
__global__ __launch_bounds__(256) void conv_silu_kernel(const float* __restrict__ xz,
    const float* __restrict__ cw, const float* __restrict__ cb,
    __hip_bfloat16* __restrict__ ucb) {
  int dir = blockIdx.y;
  int idx = blockIdx.x * 256 + threadIdx.x;
  int d = idx & (DI_ - 1), l = idx >> 9;
  const float* w = cw + (size_t)dir * DI_ * 4 + (size_t)d * 4;
  float acc = cb[(size_t)dir * DI_ + d];
  #pragma unroll
  for (int k = 0; k < 4; ++k) {
    int lf = l - 3 + k;
    if (lf >= 0) {
      int pos = dir ? (L_ - 1 - lf) : lf;
      acc = fmaf(w[k], xz[(size_t)pos * 1024 + d], acc);
    }
  }
  float s = acc * __builtin_amdgcn_rcpf(1.f + __expf(-acc));
  ucb[(size_t)dir * L_ * DI_ + (size_t)l * DI_ + d] = __float2bfloat16(s);
}

// ---------------- dt[dir][l,d] = softplus(xdb[dir][l,0:16] @ dtw[d,:] + dtb[d]) ----------------
__global__ __launch_bounds__(256) void dtproj_kernel(const float* __restrict__ xdb,
    const float* __restrict__ dtw, const float* __restrict__ dtbp, float* __restrict__ dt) {
  int dir = blockIdx.y;
  int idx = blockIdx.x * 256 + threadIdx.x;
  int d = idx & (DI_ - 1), l = idx >> 9;
  const float4* wr = (const float4*)(dtw + (size_t)dir * DI_ * 16 + (size_t)d * 16);
  const float4* xr = (const float4*)(xdb + ((size_t)dir * L_ + l) * 64);
  float acc = dtbp[(size_t)dir * DI_ + d];
  #pragma unroll
  for (int q = 0; q < 4; ++q) {
    float4 w4 = wr[q];
    float4 x4 = xr[q];
    acc = fmaf(w4.x, x4.x, fmaf(w4.y, x4.y, fmaf(w4.z, x4.z, fmaf(w4.w, x4.w, acc))));
  }
  float sp = acc > 20.f ? acc : __logf(1.f + __expf(acc));
  dt[(size_t)dir * L_ * DI_ + (size_t)l * DI_ + d] = sp;
}

// ---------------- scan pass1: per-chunk P = prod dA, Q = local scan ----------------
__global__ __launch_bounds__(256) void scan_pass1(const float* __restrict__ dt,
    const __hip_bfloat16* __restrict__ uc, const float* __restrict__ xdb,
    const float* __restrict__ A_log, float* __restrict__ Pb, float* __restrict__ Qb) {
  int dir = blockIdx.y;
  int c = blockIdx.x >> 2, q = blockIdx.x & 3;
  int tid = threadIdx.x;
  int dl = tid >> 1, nh = tid & 1;
  int d = q * 128 + dl;
  __shared__ float Bl[CH_][16];
  const float* xd = xdb + ((size_t)dir * L_ + (size_t)c * CH_) * 64;
  #pragma unroll
  for (int i = 0; i < 4; ++i) {
    int e = tid + i * 256;
    Bl[e >> 4][e & 15] = xd[(size_t)(e >> 4) * 64 + 16 + (e & 15)];
  }
  float Av[8], P[8], Q[8];
  const float* Ab = A_log + ((size_t)dir * DI_ + d) * 16 + nh * 8;
  #pragma unroll
  for (int j = 0; j < 8; ++j) { Av[j] = -__expf(Ab[j]); P[j] = 1.f; Q[j] = 0.f; }
  __syncthreads();
  const float* dtd = dt + (size_t)dir * L_ * DI_ + (size_t)c * CH_ * DI_ + d;
  const __hip_bfloat16* ud = uc + (size_t)dir * L_ * DI_ + (size_t)c * CH_ * DI_ + d;
  for (int t = 0; t < CH_; ++t) {
    float dtv = dtd[(size_t)t * DI_];
    float uv  = __bfloat162float(ud[(size_t)t * DI_]);
    float du = dtv * uv;
    const float4* Br = (const float4*)&Bl[t][nh * 8];
    float4 b0 = Br[0], b1 = Br[1];
    float bb[8] = {b0.x, b0.y, b0.z, b0.w, b1.x, b1.y, b1.z, b1.w};
    #pragma unroll
    for (int j = 0; j < 8; ++j) {
      float dA = __expf(dtv * Av[j]);
      P[j] *= dA;
      Q[j] = fmaf(dA, Q[j], bb[j] * du);
    }
  }
  size_t ob = ((size_t)dir * NC_ + c) * 8192 + (size_t)(nh * 8) * 512 + d;
  #pragma unroll
  for (int j = 0; j < 8; ++j) { Pb[ob + j * 512] = P[j]; Qb[ob + j * 512] = Q[j]; }
}

// ---------------- combine: sequential over chunks, record chunk-entry states ----------------
__global__ __launch_bounds__(256) void scan_combine(const float* __restrict__ Pb,
    const float* __restrict__ Qb, float* __restrict__ H0) {
  int idx = blockIdx.x * 256 + threadIdx.x; // 0..16383
  int dir = idx >> 13; int s = idx & 8191;
  float h = 0.f;
  for (int c = 0; c < NC_; ++c) {
    size_t o = ((size_t)dir * NC_ + c) * 8192 + s;
    H0[o] = h;
    h = fmaf(Pb[o], h, Qb[o]);
  }
}

// ---------------- scan pass2: replay with h0, emit gated y (bf16, [L][2*512]) ----------------
__global__ __launch_bounds__(256) void scan_pass2(const float* __restrict__ dt,
    const __hip_bfloat16* __restrict__ uc, const float* __restrict__ xdb,
    const float* __restrict__ A_log, const float* __restrict__ Dp,
    const float* __restrict__ xz, const float* __restrict__ H0,
    __hip_bfloat16* __restrict__ yg) {
  int dir = blockIdx.y;
  int c = blockIdx.x >> 2, q = blockIdx.x & 3;
  int tid = threadIdx.x;
  int dl = tid >> 1, nh = tid & 1;
  int d = q * 128 + dl;
  __shared__ float Bl[CH_][16];
  __shared__ float Cl[CH_][16];
  const float* xd = xdb + ((size_t)dir * L_ + (size_t)c * CH_) * 64;
  #pragma unroll
  for (int i = 0; i < 4; ++i) {
    int e = tid + i * 256;
    Bl[e >> 4][e & 15] = xd[(size_t)(e >> 4) * 64 + 16 + (e & 15)];
    Cl[e >> 4][e & 15] = xd[(size_t)(e >> 4) * 64 + 32 + (e & 15)];
  }
  float Av[8], h[8];
  const float* Ab = A_log + ((size_t)dir * DI_ + d) * 16 + nh * 8;
  size_t ob = ((size_t)dir * NC_ + c) * 8192 + (size_t)(nh * 8) * 512 + d;
  #pragma unroll
  for (int j = 0; j < 8; ++j) { Av[j] = -__expf(Ab[j]); h[j] = H0[ob + j * 512]; }
  float Dv = Dp[(size_t)dir * DI_ + d];
  __syncthreads();
  const float* dtd = dt + (size_t)dir * L_ * DI_ + (size_t)c * CH_ * DI_ + d;
  const __hip_bfloat16* ud = uc + (size_t)dir * L_ * DI_ + (size_t)c * CH_ * DI_ + d;
  for (int t = 0; t < CH_; ++t) {
    float dtv = dtd[(size_t)t * DI_];
    float uv  = __bfloat162float(ud[(size_t)t * DI_]);
    float du = dtv * uv;
    const float4* Br = (const float4*)&Bl[t][nh * 8];
    const float4* Cr = (const float4*)&Cl[t][nh * 8];
    float4 b0 = Br[0], b1 = Br[1], c0 = Cr[0], c1 = Cr[1];
    float bb[8] = {b0.x, b0.y, b0.z, b0.w, b1.x, b1.y, b1.z, b1.w};
    float cc[8] = {c0.x, c0.y, c0.z, c0.w, c1.x, c1.y, c1.z, c1.w};
    float y = 0.f;
    #pragma unroll
    for (int j = 0; j < 8; ++j) {
      float dA = __expf(dtv * Av[j]);
      h[j] = fmaf(dA, h[j], bb[j] * du);
      y = fmaf(h[j], cc[j], y);
    }
    y += __shfl_xor(y, 1, 64);
    int l = c * CH_ + t;
    int pos = dir ? (L_ - 1 - l) : l;
    float zv = xz[(size_t)pos * 1024 + DI_ + d];
    float g = zv * __builtin_amdgcn_rcpf(1.f + __expf(-zv));
    if (nh == 0)
      yg[(size_t)pos * 1024 + (size_t)dir * DI_ + d] = __float2bfloat16((y + uv * Dv) * g);
  }
}

extern "C" void kernel_launch(void* const* d_in, const int* in_sizes, int n_in,
                              void* d_out, int out_size, void* d_ws, size_t ws_size,
                              hipStream_t stream) {
  const int*   ids       = (const int*)  d_in[0];
  const float* embed_w   = (const float*)d_in[1];
  const float* norm_w    = (const float*)d_in[2];
  const float* in_proj_w = (const float*)d_in[3];
  const float* out_proj_w= (const float*)d_in[4];
  const float* conv_w    = (const float*)d_in[5];
  const float* conv_b    = (const float*)d_in[6];
  const float* x_proj_w  = (const float*)d_in[7];
  const float* dt_proj_w = (const float*)d_in[8];
  const float* dt_proj_b = (const float*)d_in[9];
  const float* A_log     = (const float*)d_in[10];
  const float* Dp        = (const float*)d_in[11];
  const float* norm_f_w  = (const float*)d_in[12];

  float* ws = (float*)d_ws;
  float* residual = ws; ws += (size_t)L_ * D_;
  float* xz       = ws; ws += (size_t)L_ * 1024;
  float* xdb      = ws; ws += (size_t)2 * L_ * 64;
  float* dtb_     = ws; ws += (size_t)2 * L_ * DI_;
  float* hbuf     = ws; ws += (size_t)L_ * D_;
  float* Pb       = ws; ws += (size_t)2 * NC_ * 8192;
  float* Qb       = ws; ws += (size_t)2 * NC_ * 8192;
  float* H0       = ws; ws += (size_t)2 * NC_ * 8192;
  __hip_bfloat16* hn_b   = (__hip_bfloat16*)ws;
  __hip_bfloat16* yg_b   = hn_b + (size_t)L_ * D_;
  __hip_bfloat16* uc_b   = yg_b + (size_t)L_ * 1024;
  __hip_bfloat16* inw_b  = uc_b + (size_t)2 * L_ * DI_;
  __hip_bfloat16* outw_b = inw_b + (size_t)4 * 1024 * D_;
  __hip_bfloat16* xpw_b  = outw_b + (size_t)4 * D_ * 1024;

  embed_kernel<<<L_ * D_ / 256, 256, 0, stream>>>(ids, embed_w, residual);
  convert_weights<<<4 * 1024 * D_ / 256, 256, 0, stream>>>(in_proj_w, out_proj_w, inw_b, outw_b);
  convert_xpw<<<4 * 2 * 64 * 512 / 256, 256, 0, stream>>>(x_proj_w, xpw_b);

  for (int i = 0; i < 4; ++i) {
    rmsnorm_kernel<true><<<L_, 256, 0, stream>>>(residual, i ? hbuf : nullptr,
                                                 norm_w + (size_t)i * D_, hn_b);
    gemm_bt_bf16<64, 64><<<dim3(1024 / 64, L_ / 64, 1), 256, 0, stream>>>(
        hn_b, inw_b + (size_t)i * 1024 * D_, xz, L_, 1024, D_, 0, 0, 0);
    dim3 gdi(L_ * DI_ / 256, 2);
    conv_silu_kernel<<<gdi, 256, 0, stream>>>(
        xz, conv_w + (size_t)i * 2 * DI_ * 4, conv_b + (size_t)i * 2 * DI_, uc_b);
    gemm_bt_bf16<64, 64><<<dim3(1, L_ / 64, 2), 256, 0, stream>>>(
        uc_b, xpw_b + (size_t)i * 2 * 64 * DI_, xdb, L_, 64, DI_,
        (size_t)L_ * DI_, (size_t)64 * DI_, (size_t)L_ * 64);
    dtproj_kernel<<<gdi, 256, 0, stream>>>(
        xdb, dt_proj_w + (size_t)i * 2 * DI_ * 16, dt_proj_b + (size_t)i * 2 * DI_, dtb_);
    dim3 gsc(NC_ * 4, 2);
    scan_pass1<<<gsc, 256, 0, stream>>>(
        dtb_, uc_b, xdb, A_log + (size_t)i * 2 * DI_ * NS_, Pb, Qb);
    scan_combine<<<64, 256, 0, stream>>>(Pb, Qb, H0);
    scan_pass2<<<gsc, 256, 0, stream>>>(
        dtb_, uc_b, xdb, A_log + (size_t)i * 2 * DI_ * NS_, Dp + (size_t)i * 2 * DI_,
        xz, H0, yg_b);
    gemm_bt_bf16<64, 64><<<dim3(D_ / 64, L_ / 64, 1), 256, 0, stream>>>(
        yg_b, outw_b + (size_t)i * D_ * 1024, hbuf, L_, D_, 1024, 0, 0, 0);
  }

  rmsnorm_kernel<false><<<L_, 256, 0, stream>>>(residual, hbuf, norm_f_w, d_out);
}

// Round 4
// 583.158 us; speedup vs baseline: 2.8979x; 1.1513x over previous
//
#include <hip/hip_runtime.h>
#include <hip/hip_bf16.h>
#include <math.h>

#define L_  4096
#define D_  256
#define DI_ 512
#define NS_ 16
#define NC_ 128
#define CH_ 32

typedef __attribute__((ext_vector_type(8))) short short8;
typedef __attribute__((ext_vector_type(4))) float f32x4;

// ---------------- embed ----------------
__global__ __launch_bounds__(256) void embed_kernel(const int* __restrict__ ids,
    const float* __restrict__ ew, float* __restrict__ res) {
  int idx = blockIdx.x * 256 + threadIdx.x;
  int l = idx >> 8, d = idx & 255;
  res[idx] = ew[ids[l] * D_ + d];
}

// ---------------- weight convert: in_proj -> bf16; out_proj -> duplicated-K bf16 ----------------
__global__ __launch_bounds__(256) void convert_weights(const float* __restrict__ inw,
    const float* __restrict__ outw, __hip_bfloat16* __restrict__ inw_b,
    __hip_bfloat16* __restrict__ outw_b) {
  int idx = blockIdx.x * 256 + threadIdx.x;   // 0 .. 4*1024*256-1
  inw_b[idx] = __float2bfloat16(inw[idx]);
  int layer = idx >> 18;
  int rem = idx & 262143;
  int o = rem >> 10, k = rem & 1023;
  outw_b[idx] = __float2bfloat16(outw[((size_t)layer * 256 + o) * 512 + (k & 511)]);
}

// ---------------- x_proj_w -> bf16 padded [4][2][64][512], rows 48..63 = 0 ----------------
__global__ __launch_bounds__(256) void convert_xpw(const float* __restrict__ xpw,
    __hip_bfloat16* __restrict__ xpw_b) {
  int idx = blockIdx.x * 256 + threadIdx.x;   // 0 .. 4*2*64*512-1
  int layer = idx >> 16;
  int rem = idx & 65535;
  int dir = rem >> 15;
  int r = (rem >> 9) & 63, k = idx & 511;
  float v = (r < 48) ? xpw[(((size_t)layer * 2 + dir) * 48 + r) * 512 + k] : 0.f;
  xpw_b[idx] = __float2bfloat16(v);
}

// ---------------- rmsnorm (optionally residual += hadd first) ----------------
template<bool BF16OUT>
__global__ __launch_bounds__(256) void rmsnorm_kernel(float* __restrict__ residual,
    const float* __restrict__ hadd, const float* __restrict__ w, void* __restrict__ out) {
  int l = blockIdx.x;
  int d = threadIdx.x;
  size_t o = (size_t)l * D_ + d;
  float v = residual[o];
  if (hadd) { v += hadd[o]; residual[o] = v; }
  float sq = v * v;
  #pragma unroll
  for (int s = 32; s > 0; s >>= 1) sq += __shfl_down(sq, s, 64);
  __shared__ float ws_[4];
  int wave = d >> 6, lane = d & 63;
  if (lane == 0) ws_[wave] = sq;
  __syncthreads();
  float total = ws_[0] + ws_[1] + ws_[2] + ws_[3];
  float scale = rsqrtf(total * (1.f / D_) + 1e-5f);
  float r = v * scale * w[d];
  if (BF16OUT) ((__hip_bfloat16*)out)[o] = __float2bfloat16(r);
  else         ((float*)out)[o] = r;
}

// ---------------- bf16 MFMA GEMM: C[m,n] = sum_k A[m,k]*B[n,k] (B^T layout), z-batched ----------------
__device__ __forceinline__ void gload_lds16(const void* g, void* l) {
  __builtin_amdgcn_global_load_lds((const __attribute__((address_space(1))) unsigned int*)g,
                                   (__attribute__((address_space(3))) unsigned int*)l,
                                   16, 0, 0);
}

template<int BM, int BN>
__global__ __launch_bounds__(256) void gemm_bt_bf16(const __hip_bfloat16* __restrict__ A,
    const __hip_bfloat16* __restrict__ B, float* __restrict__ C, int M, int N, int K,
    size_t sA, size_t sB, size_t sC) {
  A += (size_t)blockIdx.z * sA; B += (size_t)blockIdx.z * sB; C += (size_t)blockIdx.z * sC;
  constexpr int FM = BM / 32, FN = BN / 32;       // frags per wave (wave tile = BM/2 x BN/2)
  constexpr int ABYTES = BM * 64, BBYTES = BN * 64;
  __shared__ __attribute__((aligned(16))) char As[ABYTES];
  __shared__ __attribute__((aligned(16))) char Bs[BBYTES];
  int tid = threadIdx.x, lane = tid & 63, w = tid >> 6;
  int bm = blockIdx.y * BM, bn = blockIdx.x * BN;
  int wr = (w >> 1) * (BM / 2), wc = (w & 1) * (BN / 2);
  f32x4 acc[FM][FN] = {};
  for (int k0 = 0; k0 < K; k0 += 32) {
    __syncthreads();
    #pragma unroll
    for (int i = 0; i < ABYTES / 4096; ++i) {
      int x = (i * 256 + tid) * 16;
      int xs = x ^ (((x >> 7) & 3) << 4);          // inverse-swizzled SOURCE, linear dest
      int row = xs >> 6, col = (xs & 63) >> 1;
      gload_lds16(A + (size_t)(bm + row) * K + k0 + col, As + i * 4096 + w * 1024);
    }
    #pragma unroll
    for (int i = 0; i < BBYTES / 4096; ++i) {
      int x = (i * 256 + tid) * 16;
      int xs = x ^ (((x >> 7) & 3) << 4);
      int row = xs >> 6, col = (xs & 63) >> 1;
      gload_lds16(B + (size_t)(bn + row) * K + k0 + col, Bs + i * 4096 + w * 1024);
    }
    __syncthreads();
    short8 af[FM], bf[FN];
    #pragma unroll
    for (int m = 0; m < FM; ++m) {
      int row = wr + m * 16 + (lane & 15);
      int x = row * 64 + ((lane >> 4) * 16);
      x ^= ((x >> 7) & 3) << 4;                    // swizzled read
      af[m] = *reinterpret_cast<const short8*>(As + x);
    }
    #pragma unroll
    for (int n = 0; n < FN; ++n) {
      int row = wc + n * 16 + (lane & 15);
      int x = row * 64 + ((lane >> 4) * 16);
      x ^= ((x >> 7) & 3) << 4;
      bf[n] = *reinterpret_cast<const short8*>(Bs + x);
    }
    #pragma unroll
    for (int m = 0; m < FM; ++m)
      #pragma unroll
      for (int n = 0; n < FN; ++n)
        acc[m][n] = __builtin_amdgcn_mfma_f32_16x16x32_bf16(af[m], bf[n], acc[m][n], 0, 0, 0);
  }
  #pragma unroll
  for (int m = 0; m < FM; ++m)
    #pragma unroll
    for (int n = 0; n < FN; ++n)
      #pragma unroll
      for (int j = 0; j < 4; ++j)
        C[(size_t)(bm + wr + m * 16 + (lane >> 4) * 4 + j) * N + bn + wc + n * 16 + (lane & 15)]
            = acc[m][n][j];
}

// ---------------- causal depthwise conv (dir-aware) + SiLU -> bf16 ----------------
__global__ __launch_bounds__(256) void conv_silu_kernel(const float* __restrict__ xz,
    const float* __restrict__ cw, const float* __restrict__ cb,
    __hip_bfloat16* __restrict__ ucb) {
  int dir = blockIdx.y;
  int idx = blockIdx.x * 256 + threadIdx.x;
  int d = idx & (DI_ - 1), l = idx >> 9;
  const float* w = cw + (size_t)dir * DI_ * 4 + (size_t)d * 4;
  float acc = cb[(size_t)dir * DI_ + d];
  #pragma unroll
  for (int k = 0; k < 4; ++k) {
    int lf = l - 3 + k;
    if (lf >= 0) {
      int pos = dir ? (L_ - 1 - lf) : lf;
      acc = fmaf(w[k], xz[(size_t)pos * 1024 + d], acc);
    }
  }
  float s = acc * __builtin_amdgcn_rcpf(1.f + __expf(-acc));
  ucb[(size_t)dir * L_ * DI_ + (size_t)l * DI_ + d] = __float2bfloat16(s);
}

// ---------------- dt[dir][l,d] = softplus(xdb[dir][l,0:16] @ dtw[d,:] + dtb[d]) ----------------
__global__ __launch_bounds__(256) void dtproj_kernel(const float* __restrict__ xdb,
    const float* __restrict__ dtw, const float* __restrict__ dtbp, float* __restrict__ dt) {
  int dir = blockIdx.y;
  int idx = blockIdx.x * 256 + threadIdx.x;
  int d = idx & (DI_ - 1), l = idx >> 9;
  const float4* wr = (const float4*)(dtw + (size_t)dir * DI_ * 16 + (size_t)d * 16);
  const float4* xr = (const float4*)(xdb + ((size_t)dir * L_ + l) * 64);
  float acc = dtbp[(size_t)dir * DI_ + d];
  #pragma unroll
  for (int q = 0; q < 4; ++q) {
    float4 w4 = wr[q];
    float4 x4 = xr[q];
    acc = fmaf(w4.x, x4.x, fmaf(w4.y, x4.y, fmaf(w4.z, x4.z, fmaf(w4.w, x4.w, acc))));
  }
  float sp = acc > 20.f ? acc : __logf(1.f + __expf(acc));
  dt[(size_t)dir * L_ * DI_ + (size_t)l * DI_ + d] = sp;
}

// ---------------- scan pass1: LDS-staged chunk tile; P = prod dA, Q = local scan ----------------
__global__ __launch_bounds__(256) void scan_pass1(const float* __restrict__ dt,
    const __hip_bfloat16* __restrict__ uc, const float* __restrict__ xdb,
    const float* __restrict__ A_log, float* __restrict__ Pb, float* __restrict__ Qb) {
  int dir = blockIdx.y;
  int c = blockIdx.x >> 2, q = blockIdx.x & 3;
  int tid = threadIdx.x, lane = tid & 63, w = tid >> 6;
  int dl = tid >> 1, nh = tid & 1;
  int d = q * 128 + dl;
  __shared__ __attribute__((aligned(16))) float sdt[CH_][128];     // 16 KB
  __shared__ __attribute__((aligned(16))) unsigned short su[CH_][128]; // 8 KB
  __shared__ __attribute__((aligned(16))) float sB[CH_][16];       // 2 KB
  const char* dtg = (const char*)(dt + ((size_t)dir * L_ + (size_t)c * CH_) * DI_ + q * 128);
  const char* ug  = (const char*)(uc + ((size_t)dir * L_ + (size_t)c * CH_) * DI_ + q * 128);
  const char* bg  = (const char*)(xdb + ((size_t)dir * L_ + (size_t)c * CH_) * 64 + 16);
  #pragma unroll
  for (int i = 0; i < 4; ++i) {               // dt: 16 KB = 16 instr
    int idx = w * 4 + i; int byte = idx * 1024 + lane * 16;
    gload_lds16(dtg + (byte >> 9) * 2048 + (byte & 511), (char*)sdt + idx * 1024);
  }
  #pragma unroll
  for (int i = 0; i < 2; ++i) {               // u: 8 KB = 8 instr
    int idx = w * 2 + i; int byte = idx * 1024 + lane * 16;
    gload_lds16(ug + (byte >> 8) * 1024 + (byte & 255), (char*)su + idx * 1024);
  }
  if (w < 2) {                                // B: 2 KB = 2 instr
    int idx = w; int byte = idx * 1024 + lane * 16;
    gload_lds16(bg + (byte >> 6) * 256 + (byte & 63), (char*)sB + idx * 1024);
  }
  float Av[8], P[8], Q[8];
  const float4* Ab4 = (const float4*)(A_log + ((size_t)dir * DI_ + d) * 16 + nh * 8);
  float4 a0 = Ab4[0], a1 = Ab4[1];
  float al[8] = {a0.x, a0.y, a0.z, a0.w, a1.x, a1.y, a1.z, a1.w};
  #pragma unroll
  for (int j = 0; j < 8; ++j) { Av[j] = -__expf(al[j]); P[j] = 1.f; Q[j] = 0.f; }
  __syncthreads();
  #pragma unroll 2
  for (int t = 0; t < CH_; ++t) {
    float dtv = sdt[t][dl];
    float uv  = __uint_as_float((unsigned)su[t][dl] << 16);
    float du = dtv * uv;
    const float4* Br = (const float4*)&sB[t][nh * 8];
    float4 b0 = Br[0], b1 = Br[1];
    float bb[8] = {b0.x, b0.y, b0.z, b0.w, b1.x, b1.y, b1.z, b1.w};
    #pragma unroll
    for (int j = 0; j < 8; ++j) {
      float dA = __expf(dtv * Av[j]);
      P[j] *= dA;
      Q[j] = fmaf(dA, Q[j], bb[j] * du);
    }
  }
  size_t ob = ((size_t)dir * NC_ + c) * 8192 + (size_t)(nh * 8) * 512 + d;
  #pragma unroll
  for (int j = 0; j < 8; ++j) { Pb[ob + j * 512] = P[j]; Qb[ob + j * 512] = Q[j]; }
}

// ---------------- combine: sequential over chunks, record chunk-entry states ----------------
__global__ __launch_bounds__(256) void scan_combine(const float* __restrict__ Pb,
    const float* __restrict__ Qb, float* __restrict__ H0) {
  int idx = blockIdx.x * 256 + threadIdx.x; // 0..16383
  int dir = idx >> 13; int s = idx & 8191;
  size_t base = (size_t)dir * NC_ * 8192 + s;
  float h = 0.f;
  #pragma unroll 8
  for (int c = 0; c < NC_; ++c) {
    size_t o = base + (size_t)c * 8192;
    H0[o] = h;
    h = fmaf(Pb[o], h, Qb[o]);
  }
}

// ---------------- scan pass2: LDS-staged replay with h0, emit gated y (bf16, [L][2*512]) ----------------
__global__ __launch_bounds__(256) void scan_pass2(const float* __restrict__ dt,
    const __hip_bfloat16* __restrict__ uc, const float* __restrict__ xdb,
    const float* __restrict__ A_log, const float* __restrict__ Dp,
    const float* __restrict__ xz, const float* __restrict__ H0,
    __hip_bfloat16* __restrict__ yg) {
  int dir = blockIdx.y;
  int c = blockIdx.x >> 2, q = blockIdx.x & 3;
  int tid = threadIdx.x, lane = tid & 63, w = tid >> 6;
  int dl = tid >> 1, nh = tid & 1;
  int d = q * 128 + dl;
  __shared__ __attribute__((aligned(16))) float sdt[CH_][128];
  __shared__ __attribute__((aligned(16))) unsigned short su[CH_][128];
  __shared__ __attribute__((aligned(16))) float sB[CH_][16];
  __shared__ __attribute__((aligned(16))) float sC[CH_][16];
  const char* dtg = (const char*)(dt + ((size_t)dir * L_ + (size_t)c * CH_) * DI_ + q * 128);
  const char* ug  = (const char*)(uc + ((size_t)dir * L_ + (size_t)c * CH_) * DI_ + q * 128);
  const char* bg  = (const char*)(xdb + ((size_t)dir * L_ + (size_t)c * CH_) * 64 + 16);
  const char* cg  = (const char*)(xdb + ((size_t)dir * L_ + (size_t)c * CH_) * 64 + 32);
  #pragma unroll
  for (int i = 0; i < 4; ++i) {
    int idx = w * 4 + i; int byte = idx * 1024 + lane * 16;
    gload_lds16(dtg + (byte >> 9) * 2048 + (byte & 511), (char*)sdt + idx * 1024);
  }
  #pragma unroll
  for (int i = 0; i < 2; ++i) {
    int idx = w * 2 + i; int byte = idx * 1024 + lane * 16;
    gload_lds16(ug + (byte >> 8) * 1024 + (byte & 255), (char*)su + idx * 1024);
  }
  if (w < 2) {
    int idx = w; int byte = idx * 1024 + lane * 16;
    gload_lds16(bg + (byte >> 6) * 256 + (byte & 63), (char*)sB + idx * 1024);
  } else {
    int idx = w - 2; int byte = idx * 1024 + lane * 16;
    gload_lds16(cg + (byte >> 6) * 256 + (byte & 63), (char*)sC + idx * 1024);
  }
  float Av[8], h[8];
  const float4* Ab4 = (const float4*)(A_log + ((size_t)dir * DI_ + d) * 16 + nh * 8);
  float4 a0 = Ab4[0], a1 = Ab4[1];
  float al[8] = {a0.x, a0.y, a0.z, a0.w, a1.x, a1.y, a1.z, a1.w};
  size_t ob = ((size_t)dir * NC_ + c) * 8192 + (size_t)(nh * 8) * 512 + d;
  #pragma unroll
  for (int j = 0; j < 8; ++j) { Av[j] = -__expf(al[j]); h[j] = H0[ob + j * 512]; }
  float Dv = Dp[(size_t)dir * DI_ + d];
  __syncthreads();
  #pragma unroll 2
  for (int t = 0; t < CH_; ++t) {
    float dtv = sdt[t][dl];
    float uv  = __uint_as_float((unsigned)su[t][dl] << 16);
    float du = dtv * uv;
    const float4* Br = (const float4*)&sB[t][nh * 8];
    const float4* Cr = (const float4*)&sC[t][nh * 8];
    float4 b0 = Br[0], b1 = Br[1], c0 = Cr[0], c1 = Cr[1];
    float bb[8] = {b0.x, b0.y, b0.z, b0.w, b1.x, b1.y, b1.z, b1.w};
    float cc[8] = {c0.x, c0.y, c0.z, c0.w, c1.x, c1.y, c1.z, c1.w};
    float y = 0.f;
    #pragma unroll
    for (int j = 0; j < 8; ++j) {
      float dA = __expf(dtv * Av[j]);
      h[j] = fmaf(dA, h[j], bb[j] * du);
      y = fmaf(h[j], cc[j], y);
    }
    y += __shfl_xor(y, 1, 64);
    if (nh == 0) {
      int l = c * CH_ + t;
      int pos = dir ? (L_ - 1 - l) : l;
      float zv = xz[(size_t)pos * 1024 + DI_ + d];
      float g = zv * __builtin_amdgcn_rcpf(1.f + __expf(-zv));
      yg[(size_t)pos * 1024 + (size_t)dir * DI_ + d] = __float2bfloat16((y + uv * Dv) * g);
    }
  }
}

extern "C" void kernel_launch(void* const* d_in, const int* in_sizes, int n_in,
                              void* d_out, int out_size, void* d_ws, size_t ws_size,
                              hipStream_t stream) {
  const int*   ids       = (const int*)  d_in[0];
  const float* embed_w   = (const float*)d_in[1];
  const float* norm_w    = (const float*)d_in[2];
  const float* in_proj_w = (const float*)d_in[3];
  const float* out_proj_w= (const float*)d_in[4];
  const float* conv_w    = (const float*)d_in[5];
  const float* conv_b    = (const float*)d_in[6];
  const float* x_proj_w  = (const float*)d_in[7];
  const float* dt_proj_w = (const float*)d_in[8];
  const float* dt_proj_b = (const float*)d_in[9];
  const float* A_log     = (const float*)d_in[10];
  const float* Dp        = (const float*)d_in[11];
  const float* norm_f_w  = (const float*)d_in[12];

  float* ws = (float*)d_ws;
  float* residual = ws; ws += (size_t)L_ * D_;
  float* xz       = ws; ws += (size_t)L_ * 1024;
  float* xdb      = ws; ws += (size_t)2 * L_ * 64;
  float* dtb_     = ws; ws += (size_t)2 * L_ * DI_;
  float* hbuf     = ws; ws += (size_t)L_ * D_;
  float* Pb       = ws; ws += (size_t)2 * NC_ * 8192;
  float* Qb       = ws; ws += (size_t)2 * NC_ * 8192;
  float* H0       = ws; ws += (size_t)2 * NC_ * 8192;
  __hip_bfloat16* hn_b   = (__hip_bfloat16*)ws;
  __hip_bfloat16* yg_b   = hn_b + (size_t)L_ * D_;
  __hip_bfloat16* uc_b   = yg_b + (size_t)L_ * 1024;
  __hip_bfloat16* inw_b  = uc_b + (size_t)2 * L_ * DI_;
  __hip_bfloat16* outw_b = inw_b + (size_t)4 * 1024 * D_;
  __hip_bfloat16* xpw_b  = outw_b + (size_t)4 * D_ * 1024;

  embed_kernel<<<L_ * D_ / 256, 256, 0, stream>>>(ids, embed_w, residual);
  convert_weights<<<4 * 1024 * D_ / 256, 256, 0, stream>>>(in_proj_w, out_proj_w, inw_b, outw_b);
  convert_xpw<<<4 * 2 * 64 * 512 / 256, 256, 0, stream>>>(x_proj_w, xpw_b);

  for (int i = 0; i < 4; ++i) {
    rmsnorm_kernel<true><<<L_, 256, 0, stream>>>(residual, i ? hbuf : nullptr,
                                                 norm_w + (size_t)i * D_, hn_b);
    gemm_bt_bf16<64, 64><<<dim3(1024 / 64, L_ / 64, 1), 256, 0, stream>>>(
        hn_b, inw_b + (size_t)i * 1024 * D_, xz, L_, 1024, D_, 0, 0, 0);
    dim3 gdi(L_ * DI_ / 256, 2);
    conv_silu_kernel<<<gdi, 256, 0, stream>>>(
        xz, conv_w + (size_t)i * 2 * DI_ * 4, conv_b + (size_t)i * 2 * DI_, uc_b);
    gemm_bt_bf16<64, 64><<<dim3(1, L_ / 64, 2), 256, 0, stream>>>(
        uc_b, xpw_b + (size_t)i * 2 * 64 * DI_, xdb, L_, 64, DI_,
        (size_t)L_ * DI_, (size_t)64 * DI_, (size_t)L_ * 64);
    dtproj_kernel<<<gdi, 256, 0, stream>>>(
        xdb, dt_proj_w + (size_t)i * 2 * DI_ * 16, dt_proj_b + (size_t)i * 2 * DI_, dtb_);
    dim3 gsc(NC_ * 4, 2);
    scan_pass1<<<gsc, 256, 0, stream>>>(
        dtb_, uc_b, xdb, A_log + (size_t)i * 2 * DI_ * NS_, Pb, Qb);
    scan_combine<<<64, 256, 0, stream>>>(Pb, Qb, H0);
    scan_pass2<<<gsc, 256, 0, stream>>>(
        dtb_, uc_b, xdb, A_log + (size_t)i * 2 * DI_ * NS_, Dp + (size_t)i * 2 * DI_,
        xz, H0, yg_b);
    gemm_bt_bf16<64, 64><<<dim3(D_ / 64, L_ / 64, 1), 256, 0, stream>>>(
        yg_b, outw_b + (size_t)i * D_ * 1024, hbuf, L_, D_, 1024, 0, 0, 0);
  }

  rmsnorm_kernel<false><<<L_, 256, 0, stream>>>(residual, hbuf, norm_f_w, d_out);
}

// Round 5
// 506.204 us; speedup vs baseline: 3.3384x; 1.1520x over previous
//
#include <hip/hip_runtime.h>
#include <hip/hip_bf16.h>
#include <math.h>

#define L_  4096
#define D_  256
#define DI_ 512
#define NS_ 16
#define NC_ 128
#define CH_ 32

typedef __attribute__((ext_vector_type(8))) short short8;
typedef __attribute__((ext_vector_type(4))) float f32x4;

// ---------------- embed ----------------
__global__ __launch_bounds__(256) void embed_kernel(const int* __restrict__ ids,
    const float* __restrict__ ew, float* __restrict__ res) {
  int idx = blockIdx.x * 256 + threadIdx.x;
  int l = idx >> 8, d = idx & 255;
  res[idx] = ew[ids[l] * D_ + d];
}

// ---------------- weight convert: in_proj -> bf16; out_proj -> duplicated-K bf16 ----------------
__global__ __launch_bounds__(256) void convert_weights(const float* __restrict__ inw,
    const float* __restrict__ outw, __hip_bfloat16* __restrict__ inw_b,
    __hip_bfloat16* __restrict__ outw_b) {
  int idx = blockIdx.x * 256 + threadIdx.x;   // 0 .. 4*1024*256-1
  inw_b[idx] = __float2bfloat16(inw[idx]);
  int layer = idx >> 18;
  int rem = idx & 262143;
  int o = rem >> 10, k = rem & 1023;
  outw_b[idx] = __float2bfloat16(outw[((size_t)layer * 256 + o) * 512 + (k & 511)]);
}

// ---------------- x_proj_w -> bf16 padded [4][2][64][512], rows 48..63 = 0 ----------------
__global__ __launch_bounds__(256) void convert_xpw(const float* __restrict__ xpw,
    __hip_bfloat16* __restrict__ xpw_b) {
  int idx = blockIdx.x * 256 + threadIdx.x;   // 0 .. 4*2*64*512-1
  int layer = idx >> 16;
  int rem = idx & 65535;
  int dir = rem >> 15;
  int r = (rem >> 9) & 63, k = idx & 511;
  float v = (r < 48) ? xpw[(((size_t)layer * 2 + dir) * 48 + r) * 512 + k] : 0.f;
  xpw_b[idx] = __float2bfloat16(v);
}

// ---------------- rmsnorm (optionally residual += hadd first) ----------------
template<bool BF16OUT>
__global__ __launch_bounds__(256) void rmsnorm_kernel(float* __restrict__ residual,
    const float* __restrict__ hadd, const float* __restrict__ w, void* __restrict__ out) {
  int l = blockIdx.x;
  int d = threadIdx.x;
  size_t o = (size_t)l * D_ + d;
  float v = residual[o];
  if (hadd) { v += hadd[o]; residual[o] = v; }
  float sq = v * v;
  #pragma unroll
  for (int s = 32; s > 0; s >>= 1) sq += __shfl_down(sq, s, 64);
  __shared__ float ws_[4];
  int wave = d >> 6, lane = d & 63;
  if (lane == 0) ws_[wave] = sq;
  __syncthreads();
  float total = ws_[0] + ws_[1] + ws_[2] + ws_[3];
  float scale = rsqrtf(total * (1.f / D_) + 1e-5f);
  float r = v * scale * w[d];
  if (BF16OUT) ((__hip_bfloat16*)out)[o] = __float2bfloat16(r);
  else         ((float*)out)[o] = r;
}

// ---------------- bf16 MFMA GEMM: C[m,n] = sum_k A[m,k]*B[n,k] (B^T layout), z-batched ----------------
__device__ __forceinline__ void gload_lds16(const void* g, void* l) {
  __builtin_amdgcn_global_load_lds((const __attribute__((address_space(1))) unsigned int*)g,
                                   (__attribute__((address_space(3))) unsigned int*)l,
                                   16, 0, 0);
}

template<int BM, int BN, bool BF16OUT>
__global__ __launch_bounds__(256) void gemm_bt_bf16(const __hip_bfloat16* __restrict__ A,
    const __hip_bfloat16* __restrict__ B, void* __restrict__ Cv, int M, int N, int K,
    size_t sA, size_t sB, size_t sC) {
  A += (size_t)blockIdx.z * sA; B += (size_t)blockIdx.z * sB;
  constexpr int FM = BM / 32, FN = BN / 32;       // frags per wave (wave tile = BM/2 x BN/2)
  constexpr int ABYTES = BM * 64, BBYTES = BN * 64;
  __shared__ __attribute__((aligned(16))) char As[ABYTES];
  __shared__ __attribute__((aligned(16))) char Bs[BBYTES];
  int tid = threadIdx.x, lane = tid & 63, w = tid >> 6;
  int bm = blockIdx.y * BM, bn = blockIdx.x * BN;
  int wr = (w >> 1) * (BM / 2), wc = (w & 1) * (BN / 2);
  f32x4 acc[FM][FN] = {};
  for (int k0 = 0; k0 < K; k0 += 32) {
    __syncthreads();
    #pragma unroll
    for (int i = 0; i < ABYTES / 4096; ++i) {
      int x = (i * 256 + tid) * 16;
      int xs = x ^ (((x >> 7) & 3) << 4);          // inverse-swizzled SOURCE, linear dest
      int row = xs >> 6, col = (xs & 63) >> 1;
      gload_lds16(A + (size_t)(bm + row) * K + k0 + col, As + i * 4096 + w * 1024);
    }
    #pragma unroll
    for (int i = 0; i < BBYTES / 4096; ++i) {
      int x = (i * 256 + tid) * 16;
      int xs = x ^ (((x >> 7) & 3) << 4);
      int row = xs >> 6, col = (xs & 63) >> 1;
      gload_lds16(B + (size_t)(bn + row) * K + k0 + col, Bs + i * 4096 + w * 1024);
    }
    __syncthreads();
    short8 af[FM], bf[FN];
    #pragma unroll
    for (int m = 0; m < FM; ++m) {
      int row = wr + m * 16 + (lane & 15);
      int x = row * 64 + ((lane >> 4) * 16);
      x ^= ((x >> 7) & 3) << 4;                    // swizzled read
      af[m] = *reinterpret_cast<const short8*>(As + x);
    }
    #pragma unroll
    for (int n = 0; n < FN; ++n) {
      int row = wc + n * 16 + (lane & 15);
      int x = row * 64 + ((lane >> 4) * 16);
      x ^= ((x >> 7) & 3) << 4;
      bf[n] = *reinterpret_cast<const short8*>(Bs + x);
    }
    #pragma unroll
    for (int m = 0; m < FM; ++m)
      #pragma unroll
      for (int n = 0; n < FN; ++n)
        acc[m][n] = __builtin_amdgcn_mfma_f32_16x16x32_bf16(af[m], bf[n], acc[m][n], 0, 0, 0);
  }
  #pragma unroll
  for (int m = 0; m < FM; ++m)
    #pragma unroll
    for (int n = 0; n < FN; ++n)
      #pragma unroll
      for (int j = 0; j < 4; ++j) {
        size_t off = (size_t)blockIdx.z * sC +
                     (size_t)(bm + wr + m * 16 + (lane >> 4) * 4 + j) * N + bn + wc + n * 16 + (lane & 15);
        if (BF16OUT) ((__hip_bfloat16*)Cv)[off] = __float2bfloat16(acc[m][n][j]);
        else         ((float*)Cv)[off] = acc[m][n][j];
      }
}

// ---------------- causal depthwise conv (dir-aware) + SiLU -> bf16 ----------------
__global__ __launch_bounds__(256) void conv_silu_kernel(const __hip_bfloat16* __restrict__ xz,
    const float* __restrict__ cw, const float* __restrict__ cb,
    __hip_bfloat16* __restrict__ ucb) {
  int dir = blockIdx.y;
  int idx = blockIdx.x * 256 + threadIdx.x;
  int d = idx & (DI_ - 1), l = idx >> 9;
  const float* w = cw + (size_t)dir * DI_ * 4 + (size_t)d * 4;
  float acc = cb[(size_t)dir * DI_ + d];
  #pragma unroll
  for (int k = 0; k < 4; ++k) {
    int lf = l - 3 + k;
    if (lf >= 0) {
      int pos = dir ? (L_ - 1 - lf) : lf;
      acc = fmaf(w[k], __bfloat162float(xz[(size_t)pos * 1024 + d]), acc);
    }
  }
  float s = acc * __builtin_amdgcn_rcpf(1.f + __expf(-acc));
  ucb[(size_t)dir * L_ * DI_ + (size_t)l * DI_ + d] = __float2bfloat16(s);
}

// ---- shared staging helper for scan passes: sxdb[CH][64] + su[CH][128] ----
// also computes sdt[CH][128] (softplus(dtR @ dtw + dtb)) cooperatively.
__device__ __forceinline__ void scan_stage(int tid, int lane, int w, int q, int dir,
    const float* __restrict__ xdb, const __hip_bfloat16* __restrict__ uc,
    const float* __restrict__ dtw, const float* __restrict__ dtbp, int c,
    float (*sxdb)[64], unsigned short (*su)[128], float (*sdt)[128]) {
  const char* bg = (const char*)(xdb + ((size_t)dir * L_ + (size_t)c * CH_) * 64);
  const char* ug = (const char*)(uc + ((size_t)dir * L_ + (size_t)c * CH_) * DI_ + q * 128);
  // sxdb: CH*64*4 = 8KB, fully contiguous in global
  #pragma unroll
  for (int i = 0; i < 2; ++i)
    gload_lds16(bg + w * 2048 + i * 1024 + lane * 16,
                (char*)sxdb + w * 2048 + i * 1024);
  // su: CH rows of 256B slices, global row stride 1024B
  #pragma unroll
  for (int i = 0; i < 2; ++i) {
    int unit = w * 128 + i * 64 + lane;
    int byte = unit * 16;
    gload_lds16(ug + (byte >> 8) * 1024 + (byte & 255),
                (char*)su + w * 2048 + i * 1024);
  }
  __syncthreads();
  // dt compute: thread -> one dlx column, 16 t's
  int dlx = tid & 127, tst = tid >> 7;
  int dc = q * 128 + dlx;
  const float4* wr = (const float4*)(dtw + ((size_t)dir * DI_ + dc) * 16);
  float4 w0 = wr[0], w1 = wr[1], w2 = wr[2], w3 = wr[3];
  float bias = dtbp[(size_t)dir * DI_ + dc];
  #pragma unroll
  for (int i = 0; i < 16; ++i) {
    int t = tst + i * 2;
    const float4* xr = (const float4*)&sxdb[t][0];
    float4 x0 = xr[0], x1 = xr[1], x2 = xr[2], x3 = xr[3];
    float acc = bias;
    acc = fmaf(w0.x, x0.x, fmaf(w0.y, x0.y, fmaf(w0.z, x0.z, fmaf(w0.w, x0.w, acc))));
    acc = fmaf(w1.x, x1.x, fmaf(w1.y, x1.y, fmaf(w1.z, x1.z, fmaf(w1.w, x1.w, acc))));
    acc = fmaf(w2.x, x2.x, fmaf(w2.y, x2.y, fmaf(w2.z, x2.z, fmaf(w2.w, x2.w, acc))));
    acc = fmaf(w3.x, x3.x, fmaf(w3.y, x3.y, fmaf(w3.z, x3.z, fmaf(w3.w, x3.w, acc))));
    float e = __expf(fminf(acc, 20.f));
    sdt[t][dlx] = acc > 20.f ? acc : __logf(1.f + e);
  }
  __syncthreads();
}

// ---------------- scan pass1: LDS-staged chunk; P = prod dA, Q = local scan ----------------
__global__ __launch_bounds__(256) void scan_pass1(const __hip_bfloat16* __restrict__ uc,
    const float* __restrict__ xdb, const float* __restrict__ dtw,
    const float* __restrict__ dtbp, const float* __restrict__ A_log,
    float* __restrict__ Pb, float* __restrict__ Qb) {
  int dir = blockIdx.y;
  int c = blockIdx.x >> 2, q = blockIdx.x & 3;
  int tid = threadIdx.x, lane = tid & 63, w = tid >> 6;
  int dl = tid >> 1, nh = tid & 1;
  int d = q * 128 + dl;
  __shared__ __attribute__((aligned(16))) float sxdb[CH_][64];      // 8 KB
  __shared__ __attribute__((aligned(16))) unsigned short su[CH_][128]; // 8 KB
  __shared__ __attribute__((aligned(16))) float sdt[CH_][128];      // 16 KB
  float Av[8], P[8], Q[8];
  const float4* Ab4 = (const float4*)(A_log + ((size_t)dir * DI_ + d) * 16 + nh * 8);
  float4 a0 = Ab4[0], a1 = Ab4[1];
  float al[8] = {a0.x, a0.y, a0.z, a0.w, a1.x, a1.y, a1.z, a1.w};
  #pragma unroll
  for (int j = 0; j < 8; ++j) { Av[j] = -__expf(al[j]); P[j] = 1.f; Q[j] = 0.f; }
  scan_stage(tid, lane, w, q, dir, xdb, uc, dtw, dtbp, c, sxdb, su, sdt);
  #pragma unroll 2
  for (int t = 0; t < CH_; ++t) {
    float dtv = sdt[t][dl];
    float uv  = __uint_as_float((unsigned)su[t][dl] << 16);
    float du = dtv * uv;
    const float4* Br = (const float4*)&sxdb[t][16 + nh * 8];
    float4 b0 = Br[0], b1 = Br[1];
    float bb[8] = {b0.x, b0.y, b0.z, b0.w, b1.x, b1.y, b1.z, b1.w};
    #pragma unroll
    for (int j = 0; j < 8; ++j) {
      float dA = __expf(dtv * Av[j]);
      P[j] *= dA;
      Q[j] = fmaf(dA, Q[j], bb[j] * du);
    }
  }
  size_t ob = ((size_t)dir * NC_ + c) * 8192 + (size_t)(nh * 8) * 512 + d;
  #pragma unroll
  for (int j = 0; j < 8; ++j) { Pb[ob + j * 512] = P[j]; Qb[ob + j * 512] = Q[j]; }
}

// ---------------- combine: sequential over chunks, record chunk-entry states ----------------
__global__ __launch_bounds__(64) void scan_combine(const float* __restrict__ Pb,
    const float* __restrict__ Qb, float* __restrict__ H0) {
  int idx = blockIdx.x * 64 + threadIdx.x; // 0..16383
  int dir = idx >> 13; int s = idx & 8191;
  size_t base = (size_t)dir * NC_ * 8192 + s;
  float h = 0.f;
  #pragma unroll 8
  for (int c = 0; c < NC_; ++c) {
    size_t o = base + (size_t)c * 8192;
    H0[o] = h;
    h = fmaf(Pb[o], h, Qb[o]);
  }
}

// ---------------- scan pass2: LDS-staged replay with h0, emit gated y (bf16, [L][2*512]) ----------------
__global__ __launch_bounds__(256) void scan_pass2(const __hip_bfloat16* __restrict__ uc,
    const float* __restrict__ xdb, const float* __restrict__ dtw,
    const float* __restrict__ dtbp, const float* __restrict__ A_log,
    const float* __restrict__ Dp, const __hip_bfloat16* __restrict__ xz,
    const float* __restrict__ H0, __hip_bfloat16* __restrict__ yg) {
  int dir = blockIdx.y;
  int c = blockIdx.x >> 2, q = blockIdx.x & 3;
  int tid = threadIdx.x, lane = tid & 63, w = tid >> 6;
  int dl = tid >> 1, nh = tid & 1;
  int d = q * 128 + dl;
  __shared__ __attribute__((aligned(16))) float sxdb[CH_][64];
  __shared__ __attribute__((aligned(16))) unsigned short su[CH_][128];
  __shared__ __attribute__((aligned(16))) float sdt[CH_][128];
  float Av[8], h[8];
  const float4* Ab4 = (const float4*)(A_log + ((size_t)dir * DI_ + d) * 16 + nh * 8);
  float4 a0 = Ab4[0], a1 = Ab4[1];
  float al[8] = {a0.x, a0.y, a0.z, a0.w, a1.x, a1.y, a1.z, a1.w};
  size_t ob = ((size_t)dir * NC_ + c) * 8192 + (size_t)(nh * 8) * 512 + d;
  #pragma unroll
  for (int j = 0; j < 8; ++j) { Av[j] = -__expf(al[j]); h[j] = H0[ob + j * 512]; }
  float Dv = Dp[(size_t)dir * DI_ + d];
  scan_stage(tid, lane, w, q, dir, xdb, uc, dtw, dtbp, c, sxdb, su, sdt);
  #pragma unroll 2
  for (int t = 0; t < CH_; ++t) {
    float dtv = sdt[t][dl];
    float uv  = __uint_as_float((unsigned)su[t][dl] << 16);
    float du = dtv * uv;
    const float4* Br = (const float4*)&sxdb[t][16 + nh * 8];
    const float4* Cr = (const float4*)&sxdb[t][32 + nh * 8];
    float4 b0 = Br[0], b1 = Br[1], c0 = Cr[0], c1 = Cr[1];
    float bb[8] = {b0.x, b0.y, b0.z, b0.w, b1.x, b1.y, b1.z, b1.w};
    float cc[8] = {c0.x, c0.y, c0.z, c0.w, c1.x, c1.y, c1.z, c1.w};
    float y = 0.f;
    #pragma unroll
    for (int j = 0; j < 8; ++j) {
      float dA = __expf(dtv * Av[j]);
      h[j] = fmaf(dA, h[j], bb[j] * du);
      y = fmaf(h[j], cc[j], y);
    }
    y += __shfl_xor(y, 1, 64);
    if (nh == 0) {
      int l = c * CH_ + t;
      int pos = dir ? (L_ - 1 - l) : l;
      float zv = __bfloat162float(xz[(size_t)pos * 1024 + DI_ + d]);
      float g = zv * __builtin_amdgcn_rcpf(1.f + __expf(-zv));
      yg[(size_t)pos * 1024 + (size_t)dir * DI_ + d] = __float2bfloat16((y + uv * Dv) * g);
    }
  }
}

extern "C" void kernel_launch(void* const* d_in, const int* in_sizes, int n_in,
                              void* d_out, int out_size, void* d_ws, size_t ws_size,
                              hipStream_t stream) {
  const int*   ids       = (const int*)  d_in[0];
  const float* embed_w   = (const float*)d_in[1];
  const float* norm_w    = (const float*)d_in[2];
  const float* in_proj_w = (const float*)d_in[3];
  const float* out_proj_w= (const float*)d_in[4];
  const float* conv_w    = (const float*)d_in[5];
  const float* conv_b    = (const float*)d_in[6];
  const float* x_proj_w  = (const float*)d_in[7];
  const float* dt_proj_w = (const float*)d_in[8];
  const float* dt_proj_b = (const float*)d_in[9];
  const float* A_log     = (const float*)d_in[10];
  const float* Dp        = (const float*)d_in[11];
  const float* norm_f_w  = (const float*)d_in[12];

  float* ws = (float*)d_ws;
  float* residual = ws; ws += (size_t)L_ * D_;
  float* xdb      = ws; ws += (size_t)2 * L_ * 64;
  float* hbuf     = ws; ws += (size_t)L_ * D_;
  float* Pb       = ws; ws += (size_t)2 * NC_ * 8192;
  float* Qb       = ws; ws += (size_t)2 * NC_ * 8192;
  float* H0       = ws; ws += (size_t)2 * NC_ * 8192;
  __hip_bfloat16* hn_b   = (__hip_bfloat16*)ws;
  __hip_bfloat16* xz_b   = hn_b + (size_t)L_ * D_;
  __hip_bfloat16* yg_b   = xz_b + (size_t)L_ * 1024;
  __hip_bfloat16* uc_b   = yg_b + (size_t)L_ * 1024;
  __hip_bfloat16* inw_b  = uc_b + (size_t)2 * L_ * DI_;
  __hip_bfloat16* outw_b = inw_b + (size_t)4 * 1024 * D_;
  __hip_bfloat16* xpw_b  = outw_b + (size_t)4 * D_ * 1024;

  embed_kernel<<<L_ * D_ / 256, 256, 0, stream>>>(ids, embed_w, residual);
  convert_weights<<<4 * 1024 * D_ / 256, 256, 0, stream>>>(in_proj_w, out_proj_w, inw_b, outw_b);
  convert_xpw<<<4 * 2 * 64 * 512 / 256, 256, 0, stream>>>(x_proj_w, xpw_b);

  for (int i = 0; i < 4; ++i) {
    rmsnorm_kernel<true><<<L_, 256, 0, stream>>>(residual, i ? hbuf : nullptr,
                                                 norm_w + (size_t)i * D_, hn_b);
    gemm_bt_bf16<128, 64, true><<<dim3(1024 / 64, L_ / 128, 1), 256, 0, stream>>>(
        hn_b, inw_b + (size_t)i * 1024 * D_, xz_b, L_, 1024, D_, 0, 0, 0);
    dim3 gdi(L_ * DI_ / 256, 2);
    conv_silu_kernel<<<gdi, 256, 0, stream>>>(
        xz_b, conv_w + (size_t)i * 2 * DI_ * 4, conv_b + (size_t)i * 2 * DI_, uc_b);
    gemm_bt_bf16<64, 64, false><<<dim3(1, L_ / 64, 2), 256, 0, stream>>>(
        uc_b, xpw_b + (size_t)i * 2 * 64 * DI_, xdb, L_, 64, DI_,
        (size_t)L_ * DI_, (size_t)64 * DI_, (size_t)L_ * 64);
    dim3 gsc(NC_ * 4, 2);
    scan_pass1<<<gsc, 256, 0, stream>>>(
        uc_b, xdb, dt_proj_w + (size_t)i * 2 * DI_ * 16, dt_proj_b + (size_t)i * 2 * DI_,
        A_log + (size_t)i * 2 * DI_ * NS_, Pb, Qb);
    scan_combine<<<256, 64, 0, stream>>>(Pb, Qb, H0);
    scan_pass2<<<gsc, 256, 0, stream>>>(
        uc_b, xdb, dt_proj_w + (size_t)i * 2 * DI_ * 16, dt_proj_b + (size_t)i * 2 * DI_,
        A_log + (size_t)i * 2 * DI_ * NS_, Dp + (size_t)i * 2 * DI_,
        xz_b, H0, yg_b);
    gemm_bt_bf16<64, 64, false><<<dim3(D_ / 64, L_ / 64, 1), 256, 0, stream>>>(
        yg_b, outw_b + (size_t)i * D_ * 1024, hbuf, L_, D_, 1024, 0, 0, 0);
  }

  rmsnorm_kernel<false><<<L_, 256, 0, stream>>>(residual, hbuf, norm_f_w, d_out);
}

// Round 7
// 485.045 us; speedup vs baseline: 3.4841x; 1.0436x over previous
//
#include <hip/hip_runtime.h>
#include <hip/hip_bf16.h>
#include <math.h>

#define L_  4096
#define D_  256
#define DI_ 512
#define NS_ 16
#define NC_ 128
#define CH_ 32

typedef __attribute__((ext_vector_type(8))) short short8;
typedef __attribute__((ext_vector_type(4))) short short4v;
typedef __attribute__((ext_vector_type(4))) float f32x4;

// ---------------- embed ----------------
__global__ __launch_bounds__(256) void embed_kernel(const int* __restrict__ ids,
    const float* __restrict__ ew, float* __restrict__ res) {
  int idx = blockIdx.x * 256 + threadIdx.x;
  int l = idx >> 8, d = idx & 255;
  res[idx] = ew[ids[l] * D_ + d];
}

// ---------------- weight convert: in_proj -> bf16; out_proj -> duplicated-K bf16 ----------------
__global__ __launch_bounds__(256) void convert_weights(const float* __restrict__ inw,
    const float* __restrict__ outw, __hip_bfloat16* __restrict__ inw_b,
    __hip_bfloat16* __restrict__ outw_b) {
  int idx = blockIdx.x * 256 + threadIdx.x;   // 0 .. 4*1024*256-1
  inw_b[idx] = __float2bfloat16(inw[idx]);
  int layer = idx >> 18;
  int rem = idx & 262143;
  int o = rem >> 10, k = rem & 1023;
  outw_b[idx] = __float2bfloat16(outw[((size_t)layer * 256 + o) * 512 + (k & 511)]);
}

// ---------------- x_proj_w -> bf16 padded [4][2][64][512], rows 48..63 = 0 ----------------
__global__ __launch_bounds__(256) void convert_xpw(const float* __restrict__ xpw,
    __hip_bfloat16* __restrict__ xpw_b) {
  int idx = blockIdx.x * 256 + threadIdx.x;   // 0 .. 4*2*64*512-1
  int layer = idx >> 16;
  int rem = idx & 65535;
  int dir = rem >> 15;
  int r = (rem >> 9) & 63, k = idx & 511;
  float v = (r < 48) ? xpw[(((size_t)layer * 2 + dir) * 48 + r) * 512 + k] : 0.f;
  xpw_b[idx] = __float2bfloat16(v);
}

// ---------------- rmsnorm: wave-per-row, float4 ----------------
template<bool BF16OUT>
__global__ __launch_bounds__(256) void rmsnorm_kernel(float* __restrict__ residual,
    const float* __restrict__ hadd, const float* __restrict__ w, void* __restrict__ out) {
  int row = blockIdx.x * 4 + (threadIdx.x >> 6);
  int lane = threadIdx.x & 63;
  size_t o = (size_t)row * D_ + lane * 4;
  float4 v = *(const float4*)(residual + o);
  if (hadd) {
    float4 a = *(const float4*)(hadd + o);
    v.x += a.x; v.y += a.y; v.z += a.z; v.w += a.w;
    *(float4*)(residual + o) = v;
  }
  float sq = fmaf(v.x, v.x, fmaf(v.y, v.y, fmaf(v.z, v.z, v.w * v.w)));
  #pragma unroll
  for (int s = 32; s > 0; s >>= 1) sq += __shfl_xor(sq, s, 64);
  float scale = rsqrtf(sq * (1.f / D_) + 1e-5f);
  float4 wv = *(const float4*)(w + lane * 4);
  float r0 = v.x * scale * wv.x, r1 = v.y * scale * wv.y;
  float r2 = v.z * scale * wv.z, r3 = v.w * scale * wv.w;
  if (BF16OUT) {
    __hip_bfloat16* ob = (__hip_bfloat16*)out + o;
    short4v s4;
    s4[0] = __bfloat16_as_short(__float2bfloat16(r0));
    s4[1] = __bfloat16_as_short(__float2bfloat16(r1));
    s4[2] = __bfloat16_as_short(__float2bfloat16(r2));
    s4[3] = __bfloat16_as_short(__float2bfloat16(r3));
    *reinterpret_cast<short4v*>(ob) = s4;
  } else {
    float4 r = {r0, r1, r2, r3};
    *((float4*)out + (o >> 2)) = r;
  }
}

// ---------------- bf16 MFMA GEMM: C[m,n] = sum_k A[m,k]*B[n,k] (B^T layout), z-batched ----------------
__device__ __forceinline__ void gload_lds16(const void* g, void* l) {
  __builtin_amdgcn_global_load_lds((const __attribute__((address_space(1))) unsigned int*)g,
                                   (__attribute__((address_space(3))) unsigned int*)l,
                                   16, 0, 0);
}

template<int BM, int BN, bool BF16OUT>
__global__ __launch_bounds__(256) void gemm_bt_bf16(const __hip_bfloat16* __restrict__ A,
    const __hip_bfloat16* __restrict__ B, void* __restrict__ Cv, int M, int N, int K,
    size_t sA, size_t sB, size_t sC) {
  A += (size_t)blockIdx.z * sA; B += (size_t)blockIdx.z * sB;
  constexpr int FM = (BM / 2) / 16, FN = (BN / 2) / 16; // frags per wave (wave tile BM/2 x BN/2)
  constexpr int ABYTES = BM * 64, BBYTES = BN * 64;
  __shared__ __attribute__((aligned(16))) char As[ABYTES];
  __shared__ __attribute__((aligned(16))) char Bs[BBYTES];
  int tid = threadIdx.x, lane = tid & 63, w = tid >> 6;
  int bm = blockIdx.y * BM, bn = blockIdx.x * BN;
  int wr = (w >> 1) * (BM / 2), wc = (w & 1) * (BN / 2);
  f32x4 acc[FM][FN] = {};
  for (int k0 = 0; k0 < K; k0 += 32) {
    __syncthreads();
    #pragma unroll
    for (int i = 0; i < ABYTES / 4096; ++i) {
      int x = (i * 256 + tid) * 16;
      int xs = x ^ (((x >> 7) & 3) << 4);          // inverse-swizzled SOURCE, linear dest
      int row = xs >> 6, col = (xs & 63) >> 1;
      gload_lds16(A + (size_t)(bm + row) * K + k0 + col, As + i * 4096 + w * 1024);
    }
    if constexpr (ABYTES % 4096) {
      if (tid < (ABYTES % 4096) / 16) {
        int x = ((ABYTES / 4096) * 256 + tid) * 16;
        int xs = x ^ (((x >> 7) & 3) << 4);
        int row = xs >> 6, col = (xs & 63) >> 1;
        gload_lds16(A + (size_t)(bm + row) * K + k0 + col, As + (ABYTES / 4096) * 4096 + w * 1024);
      }
    }
    #pragma unroll
    for (int i = 0; i < BBYTES / 4096; ++i) {
      int x = (i * 256 + tid) * 16;
      int xs = x ^ (((x >> 7) & 3) << 4);
      int row = xs >> 6, col = (xs & 63) >> 1;
      gload_lds16(B + (size_t)(bn + row) * K + k0 + col, Bs + i * 4096 + w * 1024);
    }
    if constexpr (BBYTES % 4096) {
      if (tid < (BBYTES % 4096) / 16) {
        int x = ((BBYTES / 4096) * 256 + tid) * 16;
        int xs = x ^ (((x >> 7) & 3) << 4);
        int row = xs >> 6, col = (xs & 63) >> 1;
        gload_lds16(B + (size_t)(bn + row) * K + k0 + col, Bs + (BBYTES / 4096) * 4096 + w * 1024);
      }
    }
    __syncthreads();
    short8 af[FM], bf[FN];
    #pragma unroll
    for (int m = 0; m < FM; ++m) {
      int row = wr + m * 16 + (lane & 15);
      int x = row * 64 + ((lane >> 4) * 16);
      x ^= ((x >> 7) & 3) << 4;                    // swizzled read
      af[m] = *reinterpret_cast<const short8*>(As + x);
    }
    #pragma unroll
    for (int n = 0; n < FN; ++n) {
      int row = wc + n * 16 + (lane & 15);
      int x = row * 64 + ((lane >> 4) * 16);
      x ^= ((x >> 7) & 3) << 4;
      bf[n] = *reinterpret_cast<const short8*>(Bs + x);
    }
    #pragma unroll
    for (int m = 0; m < FM; ++m)
      #pragma unroll
      for (int n = 0; n < FN; ++n)
        acc[m][n] = __builtin_amdgcn_mfma_f32_16x16x32_bf16(af[m], bf[n], acc[m][n], 0, 0, 0);
  }
  #pragma unroll
  for (int m = 0; m < FM; ++m)
    #pragma unroll
    for (int n = 0; n < FN; ++n)
      #pragma unroll
      for (int j = 0; j < 4; ++j) {
        size_t off = (size_t)blockIdx.z * sC +
                     (size_t)(bm + wr + m * 16 + (lane >> 4) * 4 + j) * N + bn + wc + n * 16 + (lane & 15);
        if (BF16OUT) ((__hip_bfloat16*)Cv)[off] = __float2bfloat16(acc[m][n][j]);
        else         ((float*)Cv)[off] = acc[m][n][j];
      }
}

// ---------------- causal depthwise conv (dir-aware) + SiLU -> bf16 ----------------
__global__ __launch_bounds__(256) void conv_silu_kernel(const __hip_bfloat16* __restrict__ xz,
    const float* __restrict__ cw, const float* __restrict__ cb,
    __hip_bfloat16* __restrict__ ucb) {
  int dir = blockIdx.y;
  int idx = blockIdx.x * 256 + threadIdx.x;
  int d = idx & (DI_ - 1), l = idx >> 9;
  const float* w = cw + (size_t)dir * DI_ * 4 + (size_t)d * 4;
  float acc = cb[(size_t)dir * DI_ + d];
  #pragma unroll
  for (int k = 0; k < 4; ++k) {
    int lf = l - 3 + k;
    if (lf >= 0) {
      int pos = dir ? (L_ - 1 - lf) : lf;
      acc = fmaf(w[k], __bfloat162float(xz[(size_t)pos * 1024 + d]), acc);
    }
  }
  float s = acc * __builtin_amdgcn_rcpf(1.f + __expf(-acc));
  ucb[(size_t)dir * L_ * DI_ + (size_t)l * DI_ + d] = __float2bfloat16(s);
}

// ---- staging helper: sxdb[CH][64] + su[CH][128] + cooperative dt -> sdt[CH][128] ----
__device__ __forceinline__ void scan_stage(int tid, int lane, int w, int q, int dir,
    const float* __restrict__ xdb, const __hip_bfloat16* __restrict__ uc,
    const float* __restrict__ dtw, const float* __restrict__ dtbp, int c,
    float (*sxdb)[64], unsigned short (*su)[128], float (*sdt)[128]) {
  const char* bg = (const char*)(xdb + ((size_t)dir * L_ + (size_t)c * CH_) * 64);
  const char* ug = (const char*)(uc + ((size_t)dir * L_ + (size_t)c * CH_) * DI_ + q * 128);
  #pragma unroll
  for (int i = 0; i < 2; ++i)
    gload_lds16(bg + w * 2048 + i * 1024 + lane * 16,
                (char*)sxdb + w * 2048 + i * 1024);
  #pragma unroll
  for (int i = 0; i < 2; ++i) {
    int unit = w * 128 + i * 64 + lane;
    int byte = unit * 16;
    gload_lds16(ug + (byte >> 8) * 1024 + (byte & 255),
                (char*)su + w * 2048 + i * 1024);
  }
  __syncthreads();
  int dlx = tid & 127, tst = tid >> 7;
  int dc = q * 128 + dlx;
  const float4* wr = (const float4*)(dtw + ((size_t)dir * DI_ + dc) * 16);
  float4 w0 = wr[0], w1 = wr[1], w2 = wr[2], w3 = wr[3];
  float bias = dtbp[(size_t)dir * DI_ + dc];
  #pragma unroll
  for (int i = 0; i < 16; ++i) {
    int t = tst + i * 2;
    const float4* xr = (const float4*)&sxdb[t][0];
    float4 x0 = xr[0], x1 = xr[1], x2 = xr[2], x3 = xr[3];
    float acc = bias;
    acc = fmaf(w0.x, x0.x, fmaf(w0.y, x0.y, fmaf(w0.z, x0.z, fmaf(w0.w, x0.w, acc))));
    acc = fmaf(w1.x, x1.x, fmaf(w1.y, x1.y, fmaf(w1.z, x1.z, fmaf(w1.w, x1.w, acc))));
    acc = fmaf(w2.x, x2.x, fmaf(w2.y, x2.y, fmaf(w2.z, x2.z, fmaf(w2.w, x2.w, acc))));
    acc = fmaf(w3.x, x3.x, fmaf(w3.y, x3.y, fmaf(w3.z, x3.z, fmaf(w3.w, x3.w, acc))));
    float e = __expf(fminf(acc, 20.f));
    sdt[t][dlx] = acc > 20.f ? acc : __logf(1.f + e);
  }
  __syncthreads();
}

// ---------------- scan pass1: LDS-staged chunk; P = prod dA, Q = local scan ----------------
__global__ __launch_bounds__(256) void scan_pass1(const __hip_bfloat16* __restrict__ uc,
    const float* __restrict__ xdb, const float* __restrict__ dtw,
    const float* __restrict__ dtbp, const float* __restrict__ A_log,
    float* __restrict__ Pb, float* __restrict__ Qb) {
  int dir = blockIdx.y;
  int c = blockIdx.x >> 2, q = blockIdx.x & 3;
  int tid = threadIdx.x, lane = tid & 63, w = tid >> 6;
  int dl = tid >> 1, nh = tid & 1;
  int d = q * 128 + dl;
  __shared__ __attribute__((aligned(16))) float sxdb[CH_][64];      // 8 KB
  __shared__ __attribute__((aligned(16))) unsigned short su[CH_][128]; // 8 KB
  __shared__ __attribute__((aligned(16))) float sdt[CH_][128];      // 16 KB
  float Av[8], P[8], Q[8];
  const float4* Ab4 = (const float4*)(A_log + ((size_t)dir * DI_ + d) * 16 + nh * 8);
  float4 a0 = Ab4[0], a1 = Ab4[1];
  float al[8] = {a0.x, a0.y, a0.z, a0.w, a1.x, a1.y, a1.z, a1.w};
  #pragma unroll
  for (int j = 0; j < 8; ++j) { Av[j] = -__expf(al[j]); P[j] = 1.f; Q[j] = 0.f; }
  scan_stage(tid, lane, w, q, dir, xdb, uc, dtw, dtbp, c, sxdb, su, sdt);
  #pragma unroll 2
  for (int t = 0; t < CH_; ++t) {
    float dtv = sdt[t][dl];
    float uv  = __uint_as_float((unsigned)su[t][dl] << 16);
    float du = dtv * uv;
    const float4* Br = (const float4*)&sxdb[t][16 + nh * 8];
    float4 b0 = Br[0], b1 = Br[1];
    float bb[8] = {b0.x, b0.y, b0.z, b0.w, b1.x, b1.y, b1.z, b1.w};
    #pragma unroll
    for (int j = 0; j < 8; ++j) {
      float dA = __expf(dtv * Av[j]);
      P[j] *= dA;
      Q[j] = fmaf(dA, Q[j], bb[j] * du);
    }
  }
  size_t ob = ((size_t)dir * NC_ + c) * 8192 + (size_t)(nh * 8) * 512 + d;
  #pragma unroll
  for (int j = 0; j < 8; ++j) { Pb[ob + j * 512] = P[j]; Qb[ob + j * 512] = Q[j]; }
}

// ---------------- combine: sequential over chunks, record chunk-entry states ----------------
__global__ __launch_bounds__(64) void scan_combine(const float* __restrict__ Pb,
    const float* __restrict__ Qb, float* __restrict__ H0) {
  int idx = blockIdx.x * 64 + threadIdx.x; // 0..16383
  int dir = idx >> 13; int s = idx & 8191;
  size_t base = (size_t)dir * NC_ * 8192 + s;
  float h = 0.f;
  #pragma unroll 8
  for (int c = 0; c < NC_; ++c) {
    size_t o = base + (size_t)c * 8192;
    H0[o] = h;
    h = fmaf(Pb[o], h, Qb[o]);
  }
}

// ---------------- scan pass2: LDS-staged replay with h0, emit gated y (bf16, [L][2*512]) ----------------
__global__ __launch_bounds__(256) void scan_pass2(const __hip_bfloat16* __restrict__ uc,
    const float* __restrict__ xdb, const float* __restrict__ dtw,
    const float* __restrict__ dtbp, const float* __restrict__ A_log,
    const float* __restrict__ Dp, const __hip_bfloat16* __restrict__ xz,
    const float* __restrict__ H0, __hip_bfloat16* __restrict__ yg) {
  int dir = blockIdx.y;
  int c = blockIdx.x >> 2, q = blockIdx.x & 3;
  int tid = threadIdx.x, lane = tid & 63, w = tid >> 6;
  int dl = tid >> 1, nh = tid & 1;
  int d = q * 128 + dl;
  __shared__ __attribute__((aligned(16))) float sxdb[CH_][64];
  __shared__ __attribute__((aligned(16))) unsigned short su[CH_][128];
  __shared__ __attribute__((aligned(16))) float sdt[CH_][128];
  float Av[8], h[8];
  const float4* Ab4 = (const float4*)(A_log + ((size_t)dir * DI_ + d) * 16 + nh * 8);
  float4 a0 = Ab4[0], a1 = Ab4[1];
  float al[8] = {a0.x, a0.y, a0.z, a0.w, a1.x, a1.y, a1.z, a1.w};
  size_t ob = ((size_t)dir * NC_ + c) * 8192 + (size_t)(nh * 8) * 512 + d;
  #pragma unroll
  for (int j = 0; j < 8; ++j) { Av[j] = -__expf(al[j]); h[j] = H0[ob + j * 512]; }
  float Dv = Dp[(size_t)dir * DI_ + d];
  scan_stage(tid, lane, w, q, dir, xdb, uc, dtw, dtbp, c, sxdb, su, sdt);
  #pragma unroll 2
  for (int t = 0; t < CH_; ++t) {
    float dtv = sdt[t][dl];
    float uv  = __uint_as_float((unsigned)su[t][dl] << 16);
    float du = dtv * uv;
    const float4* Br = (const float4*)&sxdb[t][16 + nh * 8];
    const float4* Cr = (const float4*)&sxdb[t][32 + nh * 8];
    float4 b0 = Br[0], b1 = Br[1], c0 = Cr[0], c1 = Cr[1];
    float bb[8] = {b0.x, b0.y, b0.z, b0.w, b1.x, b1.y, b1.z, b1.w};
    float cc[8] = {c0.x, c0.y, c0.z, c0.w, c1.x, c1.y, c1.z, c1.w};
    float y = 0.f;
    #pragma unroll
    for (int j = 0; j < 8; ++j) {
      float dA = __expf(dtv * Av[j]);
      h[j] = fmaf(dA, h[j], bb[j] * du);
      y = fmaf(h[j], cc[j], y);
    }
    y += __shfl_xor(y, 1, 64);
    if (nh == 0) {
      int l = c * CH_ + t;
      int pos = dir ? (L_ - 1 - l) : l;
      float zv = __bfloat162float(xz[(size_t)pos * 1024 + DI_ + d]);
      float g = zv * __builtin_amdgcn_rcpf(1.f + __expf(-zv));
      yg[(size_t)pos * 1024 + (size_t)dir * DI_ + d] = __float2bfloat16((y + uv * Dv) * g);
    }
  }
}

extern "C" void kernel_launch(void* const* d_in, const int* in_sizes, int n_in,
                              void* d_out, int out_size, void* d_ws, size_t ws_size,
                              hipStream_t stream) {
  const int*   ids       = (const int*)  d_in[0];
  const float* embed_w   = (const float*)d_in[1];
  const float* norm_w    = (const float*)d_in[2];
  const float* in_proj_w = (const float*)d_in[3];
  const float* out_proj_w= (const float*)d_in[4];
  const float* conv_w    = (const float*)d_in[5];
  const float* conv_b    = (const float*)d_in[6];
  const float* x_proj_w  = (const float*)d_in[7];
  const float* dt_proj_w = (const float*)d_in[8];
  const float* dt_proj_b = (const float*)d_in[9];
  const float* A_log     = (const float*)d_in[10];
  const float* Dp        = (const float*)d_in[11];
  const float* norm_f_w  = (const float*)d_in[12];

  float* ws = (float*)d_ws;
  float* residual = ws; ws += (size_t)L_ * D_;
  float* xdb      = ws; ws += (size_t)2 * L_ * 64;
  float* hbuf     = ws; ws += (size_t)L_ * D_;
  float* Pb       = ws; ws += (size_t)2 * NC_ * 8192;
  float* Qb       = ws; ws += (size_t)2 * NC_ * 8192;
  float* H0       = ws; ws += (size_t)2 * NC_ * 8192;
  __hip_bfloat16* hn_b   = (__hip_bfloat16*)ws;
  __hip_bfloat16* xz_b   = hn_b + (size_t)L_ * D_;
  __hip_bfloat16* yg_b   = xz_b + (size_t)L_ * 1024;
  __hip_bfloat16* uc_b   = yg_b + (size_t)L_ * 1024;
  __hip_bfloat16* inw_b  = uc_b + (size_t)2 * L_ * DI_;
  __hip_bfloat16* outw_b = inw_b + (size_t)4 * 1024 * D_;
  __hip_bfloat16* xpw_b  = outw_b + (size_t)4 * D_ * 1024;

  embed_kernel<<<L_ * D_ / 256, 256, 0, stream>>>(ids, embed_w, residual);
  convert_weights<<<4 * 1024 * D_ / 256, 256, 0, stream>>>(in_proj_w, out_proj_w, inw_b, outw_b);
  convert_xpw<<<4 * 2 * 64 * 512 / 256, 256, 0, stream>>>(x_proj_w, xpw_b);

  for (int i = 0; i < 4; ++i) {
    rmsnorm_kernel<true><<<L_ / 4, 256, 0, stream>>>(residual, i ? hbuf : nullptr,
                                                     norm_w + (size_t)i * D_, hn_b);
    gemm_bt_bf16<128, 64, true><<<dim3(1024 / 64, L_ / 128, 1), 256, 0, stream>>>(
        hn_b, inw_b + (size_t)i * 1024 * D_, xz_b, L_, 1024, D_, 0, 0, 0);
    dim3 gdi(L_ * DI_ / 256, 2);
    conv_silu_kernel<<<gdi, 256, 0, stream>>>(
        xz_b, conv_w + (size_t)i * 2 * DI_ * 4, conv_b + (size_t)i * 2 * DI_, uc_b);
    gemm_bt_bf16<32, 64, false><<<dim3(1, L_ / 32, 2), 256, 0, stream>>>(
        uc_b, xpw_b + (size_t)i * 2 * 64 * DI_, xdb, L_, 64, DI_,
        (size_t)L_ * DI_, (size_t)64 * DI_, (size_t)L_ * 64);
    dim3 gsc(NC_ * 4, 2);
    scan_pass1<<<gsc, 256, 0, stream>>>(
        uc_b, xdb, dt_proj_w + (size_t)i * 2 * DI_ * 16, dt_proj_b + (size_t)i * 2 * DI_,
        A_log + (size_t)i * 2 * DI_ * NS_, Pb, Qb);
    scan_combine<<<256, 64, 0, stream>>>(Pb, Qb, H0);
    scan_pass2<<<gsc, 256, 0, stream>>>(
        uc_b, xdb, dt_proj_w + (size_t)i * 2 * DI_ * 16, dt_proj_b + (size_t)i * 2 * DI_,
        A_log + (size_t)i * 2 * DI_ * NS_, Dp + (size_t)i * 2 * DI_,
        xz_b, H0, yg_b);
    gemm_bt_bf16<64, 64, false><<<dim3(D_ / 64, L_ / 64, 1), 256, 0, stream>>>(
        yg_b, outw_b + (size_t)i * D_ * 1024, hbuf, L_, D_, 1024, 0, 0, 0);
  }

  rmsnorm_kernel<false><<<L_ / 4, 256, 0, stream>>>(residual, hbuf, norm_f_w, d_out);
}